// Round 1
// 259.583 us; speedup vs baseline: 1.0052x; 1.0052x over previous
//
#include <hip/hip_runtime.h>

#define KDIM 1024

typedef _Float16 half8 __attribute__((ext_vector_type(8)));
typedef _Float16 half4 __attribute__((ext_vector_type(4)));
typedef __fp16 fp16x2 __attribute__((ext_vector_type(2)));
typedef __fp16 fp16x4 __attribute__((ext_vector_type(4)));
typedef float f32x4 __attribute__((ext_vector_type(4)));

#if defined(__has_builtin)
#if __has_builtin(__builtin_amdgcn_global_load_lds)
#define HAVE_GLDS 1
#endif
#if __has_builtin(__builtin_amdgcn_exp2f)
#define EXP2(x) __builtin_amdgcn_exp2f(x)
#endif
#if __has_builtin(__builtin_amdgcn_cvt_pkrtz)
#define HAVE_PKRTZ 1
#endif
#if __has_builtin(__builtin_amdgcn_fdot2)
#define HAVE_FDOT2 1
#endif
#endif
#ifndef EXP2
#define EXP2(x) exp2f(x)
#endif

__device__ __forceinline__ void stage16(const _Float16* g, _Float16* wave_base, int lane) {
#ifdef HAVE_GLDS
  __builtin_amdgcn_global_load_lds(
      (const __attribute__((address_space(1))) void*)g,
      (__attribute__((address_space(3))) void*)wave_base, 16, 0, 0);
#else
  *(half8*)(wave_base + lane * 8) = *(const half8*)g;
#endif
}

#define BARRIER() __builtin_amdgcn_s_barrier()
#define LGKM0()                                         \
  do {                                                  \
    asm volatile("s_waitcnt lgkmcnt(0)" ::: "memory");  \
    __builtin_amdgcn_sched_barrier(0);                  \
  } while (0)
#define VMCNT(n)                                               \
  do {                                                         \
    asm volatile("s_waitcnt vmcnt(" #n ")" ::: "memory");      \
  } while (0)

// ------------- merged prep: cast x | transpose-cast W | mask bits -------------
__global__ void prep_kernel(const float* __restrict__ x, const float* __restrict__ am,
                            const float* __restrict__ Wq, const float* __restrict__ Wk,
                            const float* __restrict__ Wv, _Float16* __restrict__ xb,
                            _Float16* __restrict__ Wqkvt, unsigned long long* __restrict__ bits) {
  __shared__ _Float16 tile[32][33];
  int bid = blockIdx.x;
  if (bid < 8192) {
    size_t i = ((size_t)bid * 256 + threadIdx.x) * 4;
    float4 v = *(const float4*)(x + i);
    half4 h = { (_Float16)v.x, (_Float16)v.y, (_Float16)v.z, (_Float16)v.w };
    *(half4*)(xb + i) = h;
  } else if (bid < 11264) {
    int zz = bid - 8192;
    int z = zz >> 10;
    int rem = zz & 1023;
    int bx = rem & 31, by = rem >> 5;
    const float* src = z == 0 ? Wq : (z == 1 ? Wk : Wv);
    _Float16* dst = Wqkvt + (size_t)z * KDIM * KDIM;
    float sc = (z == 0) ? 0.18033688011112042f : 1.0f;  // (1/8)*log2(e)
    int tx = threadIdx.x & 31, ty = threadIdx.x >> 5;
    int c0 = bx * 32, r0 = by * 32;
#pragma unroll
    for (int i = 0; i < 4; i++) {
      int r = r0 + ty + i * 8;
      tile[tx][ty + i * 8] = (_Float16)(src[(size_t)r * KDIM + c0 + tx] * sc);
    }
    __syncthreads();
#pragma unroll
    for (int i = 0; i < 4; i++) {
      int n = c0 + ty + i * 8;
      dst[(size_t)n * KDIM + r0 + tx] = tile[ty + i * 8][tx];
    }
  } else {
    size_t i = (size_t)(bid - 11264) * 256 + threadIdx.x;
    unsigned long long b = __ballot(am[i] != 0.0f);
    if ((threadIdx.x & 63) == 0) bits[i >> 6] = b;
  }
}

// ---------------- fused QKV GEMM, 256x256 tile, BK=64, 8-phase counted-vmcnt ----------------
template <int MH, int NH>
__device__ __forceinline__ void mfma_quad(f32x4 (&acc)[8][4], const half8 (&af)[4][2],
                                          const half8 (&bf)[2][2]) {
  __builtin_amdgcn_s_setprio(1);
#pragma unroll
  for (int mi = 0; mi < 4; ++mi)
#pragma unroll
    for (int nj = 0; nj < 2; ++nj) {
      acc[MH * 4 + mi][NH * 2 + nj] = __builtin_amdgcn_mfma_f32_16x16x32_f16(
          af[mi][0], bf[nj][0], acc[MH * 4 + mi][NH * 2 + nj], 0, 0, 0);
      acc[MH * 4 + mi][NH * 2 + nj] = __builtin_amdgcn_mfma_f32_16x16x32_f16(
          af[mi][1], bf[nj][1], acc[MH * 4 + mi][NH * 2 + nj], 0, 0, 0);
    }
  __builtin_amdgcn_s_setprio(0);
}

__global__ __launch_bounds__(512, 2)
void gemm_kernel(const _Float16* __restrict__ A, const _Float16* __restrict__ Bt,
                 _Float16* __restrict__ Qt, _Float16* __restrict__ Kh,
                 _Float16* __restrict__ Vth) {
  // LDS: [buf][half(128 rows)][row][64] f16, XOR-swizzled in 16B chunks within each row.
  __shared__ _Float16 As[2 * 16384];
  __shared__ _Float16 Bs[2 * 16384];
  int tid = threadIdx.x;
  int lane = tid & 63, w = tid >> 6;
  int la = lane & 15, qd = lane >> 4;
  int wm = w & 1, wn = w >> 1;  // 2M x 4N waves; wave tile 128x64 interleaved across halves
  // XCD-aware swizzle: 384 blocks, 48 consecutive wgs per XCD (384 % 8 == 0 -> bijective)
  int bid = blockIdx.x;
  int wg = (bid & 7) * 48 + (bid >> 3);
  int by = wg / 12, bx = wg - by * 12;
  int m0 = by * 256, n0 = bx * 256;
  // staging geometry: thread -> row (tid>>3) + 64*l, 16B chunk (tid&7); source pre-swizzled
  int srow = tid >> 3;
  int scc = ((srow & 7) ^ (tid & 7)) << 3;  // pre-swizzled source chunk (halves)
  // read-side swizzled chunk offsets for k=0/k=1 (halves)
  const int rc0 = ((qd ^ (la & 7)) << 3);
  const int rc1 = (((4 | qd) ^ (la & 7)) << 3);

  const _Float16* Ab = A + (size_t)m0 * KDIM;
  const _Float16* Bb = Bt + (size_t)n0 * KDIM;

  auto stA = [&](int buf, int h, int kt) {
#pragma unroll
    for (int l = 0; l < 2; ++l) {
      int r = h * 128 + srow + l * 64;
      stage16(Ab + (size_t)r * KDIM + kt + scc,
              As + buf * 16384 + h * 8192 + l * 4096 + w * 512, lane);
    }
  };
  auto stB = [&](int buf, int h, int kt) {
#pragma unroll
    for (int l = 0; l < 2; ++l) {
      int r = h * 128 + srow + l * 64;
      stage16(Bb + (size_t)r * KDIM + kt + scc,
              Bs + buf * 16384 + h * 8192 + l * 4096 + w * 512, lane);
    }
  };

  f32x4 acc[8][4] = {};
  half8 af[4][2], bf[2][2];

  auto ldAf = [&](int buf, int mh) {
#pragma unroll
    for (int mi = 0; mi < 4; ++mi) {
      const _Float16* p = As + buf * 16384 + mh * 8192 + (wm * 64 + mi * 16 + la) * 64;
      af[mi][0] = *(const half8*)(p + rc0);
      af[mi][1] = *(const half8*)(p + rc1);
    }
  };
  auto ldBf = [&](int buf, int nh) {
#pragma unroll
    for (int nj = 0; nj < 2; ++nj) {
      const _Float16* p = Bs + buf * 16384 + nh * 8192 + (wn * 32 + nj * 16 + la) * 64;
      bf[nj][0] = *(const half8*)(p + rc0);
      bf[nj][1] = *(const half8*)(p + rc1);
    }
  };

  // Prologue: tile0 fully (A0,A1,B0,B1) + tile1 (A0,B0). vmcnt(4) leaves tile1's 2 halves in flight.
  stA(0, 0, 0); stA(0, 1, 0); stB(0, 0, 0); stB(0, 1, 0);
  stA(1, 0, 64); stB(1, 0, 64);
  VMCNT(4);
  BARRIER();

  for (int t = 0; t < 16; ++t) {
    int cur = t & 1, nxt = cur ^ 1;
    int k1 = (t + 1) << 6, k2 = (t + 2) << 6;
    // phase 1: quadrant (mh=0,nh=0); stage (t+1).A1 -> nxt (last read at t-1 ph3/4)
    ldAf(cur, 0);
    ldBf(cur, 0);
    if (t < 15) stA(nxt, 1, k1);
    BARRIER();
    LGKM0();
    mfma_quad<0, 0>(acc, af, bf);
    BARRIER();
    // phase 2: (0,1) reuse af; stage (t+1).B1 -> nxt
    ldBf(cur, 1);
    if (t < 15) stB(nxt, 1, k1);
    BARRIER();
    LGKM0();
    mfma_quad<0, 1>(acc, af, bf);
    BARRIER();
    // phase 3: (1,0); stage (t+2).A0 -> cur.A0 (cur.A0 last read in ph1)
    ldAf(cur, 1);
    ldBf(cur, 0);
    if (t < 14) stA(cur, 0, k2);
    BARRIER();
    LGKM0();
    mfma_quad<1, 0>(acc, af, bf);
    BARRIER();
    // phase 4: (1,1); stage (t+2).B0 -> cur.B0 (cur.B0 last read in ph3)
    ldBf(cur, 1);
    if (t < 14) stB(cur, 0, k2);
    BARRIER();
    LGKM0();
    mfma_quad<1, 1>(acc, af, bf);
    // counted wait: leaves {(t+2).A0,(t+2).B0} (4 loads) in flight; everything tile t+1
    // reads is now retired. Tail (t==14): no t+2 stages were issued, so drain.
    if (t < 14) { VMCNT(4); } else { VMCNT(0); }
    BARRIER();
  }

  // ---------------- epilogue ----------------
  int which = n0 >> 10;  // 0:Q 1:K 2:V (uniform per block; 1024 % 256 == 0)
  int n0k = n0 & 1023;
  if (which == 1) {
#pragma unroll
    for (int mh = 0; mh < 2; ++mh) {
      int srow0 = m0 + mh * 128 + wm * 64;
      int b = srow0 >> 10, s0 = srow0 & 1023;
#pragma unroll
      for (int nh = 0; nh < 2; ++nh)
#pragma unroll
        for (int nj = 0; nj < 2; ++nj) {
          int colh = n0k + nh * 128 + wn * 32 + nj * 16;
          int hh = colh >> 6;
          int d = (colh & 63) + la;
          _Float16* kb = Kh + (size_t)(b * 16 + hh) * 1024 * 64;
#pragma unroll
          for (int mi = 0; mi < 4; ++mi) {
            f32x4 v = acc[mh * 4 + mi][nh * 2 + nj];
            int s = s0 + mi * 16 + qd * 4;
#pragma unroll
            for (int rg = 0; rg < 4; ++rg)
              kb[(size_t)(s + rg) * 64 + d] = (_Float16)v[rg];
          }
        }
    }
  } else {
    _Float16* dst = (which == 0) ? Qt : Vth;
    // wave-private 16x72 transpose patch in As (all waves past final barrier)
    _Float16* ep = As + w * 1280;
    int rr = lane >> 2, c4 = lane & 3;
#pragma unroll
    for (int mh = 0; mh < 2; ++mh) {
      int srow0 = m0 + mh * 128 + wm * 64;
      int b = srow0 >> 10, s0 = srow0 & 1023;
#pragma unroll
      for (int nh = 0; nh < 2; ++nh)
#pragma unroll
        for (int nj = 0; nj < 2; ++nj) {
          int colh = n0k + nh * 128 + wn * 32 + nj * 16;
          int hh = colh >> 6, d0 = colh & 63;
#pragma unroll
          for (int mi = 0; mi < 4; ++mi) {
            f32x4 v = acc[mh * 4 + mi][nh * 2 + nj];
            half4 hv = { (_Float16)v[0], (_Float16)v[1], (_Float16)v[2], (_Float16)v[3] };
            *(half4*)(ep + la * 72 + mi * 16 + qd * 4) = hv;  // row=d(la), col=s
          }
          half8 o0 = *(const half8*)(ep + rr * 72 + c4 * 16);
          half8 o1 = *(const half8*)(ep + rr * 72 + c4 * 16 + 8);
          _Float16* gp = dst + ((size_t)(b * 16 + hh) * 64 + d0 + rr) * 1024 + s0 + c4 * 16;
          *(half8*)gp = o0;
          *(half8*)(gp + 8) = o1;
        }
    }
  }
}

// ---------------- fused attention (unchanged) ----------------
__global__ __launch_bounds__(512, 2)
void attn_kernel(const _Float16* __restrict__ Qt, const _Float16* __restrict__ K,
                 const _Float16* __restrict__ Vt, const unsigned long long* __restrict__ mbits,
                 float* __restrict__ out) {
  __shared__ _Float16 Ks[2][2 * 64 * 32];  // [buf][ks=d/32][t][32]
  __shared__ _Float16 Vs[2][2 * 64 * 40];  // [buf][tc=t/32][d][40 padded]
  int tid = threadIdx.x;
  int lane = tid & 63, w4 = tid >> 6;  // w4 0..7
  int la = lane & 15, qd = lane >> 4;
  int linear = blockIdx.x;
  int xlo = linear & 7;
  int tmp = linear >> 3;  // 0..63
  int qt = tmp & 3;
  int hb = (tmp >> 2) * 8 + xlo;  // 0..127
  int h = hb & 15, b = hb >> 4;
  const _Float16* Qp = Qt + (size_t)hb * 64 * 1024;  // [d][s]
  const _Float16* Kp = K + (size_t)hb * 1024 * 64;   // [s][d]
  const _Float16* Vp = Vt + (size_t)hb * 64 * 1024;  // [d][s]
  int q0w = qt * 256 + w4 * 16;  // qfrag qi adds qi*128
  half8 qf[2][2];
#pragma unroll
  for (int qi = 0; qi < 2; qi++)
#pragma unroll
    for (int ks = 0; ks < 2; ks++)
#pragma unroll
      for (int j = 0; j < 8; j++)
        qf[qi][ks][j] = Qp[(size_t)(ks * 32 + qd * 8 + j) * 1024 + q0w + qi * 128 + la];
  unsigned long long mq[2][4];
#pragma unroll
  for (int qi = 0; qi < 2; qi++) {
    const ulonglong2* mp =
        (const ulonglong2*)(mbits + ((size_t)b * 1024 + q0w + qi * 128 + la) * 16 + qd * 4);
    ulonglong2 m01 = mp[0];
    ulonglong2 m23 = mp[1];
    mq[qi][0] = m01.x; mq[qi][1] = m01.y; mq[qi][2] = m23.x; mq[qi][3] = m23.y;
  }
  f32x4 acco[2][4] = {};
  float rs[2] = {0.f, 0.f};
  int kt_t = (tid & 255) >> 2;
  int kt_d = (tid >> 8) * 32 + (tid & 3) * 8;
  int vd = tid >> 3;
  int vt = (tid & 7) * 8;
  int vs_off = (vt >= 32 ? 2560 : 0) + vd * 40 + (vt & 31);
#if defined(HAVE_FDOT2) && defined(HAVE_PKRTZ)
  fp16x2 one2 = { (__fp16)1.0f, (__fp16)1.0f };
#endif
  {
    stage16(Kp + (size_t)kt_t * 64 + kt_d, Ks[0] + w4 * 512, lane);
    half8 vv = *(const half8*)(Vp + (size_t)vd * 1024 + vt);
    *(half8*)(Vs[0] + vs_off) = vv;
  }
  __syncthreads();
  for (int tt = 0; tt < 16; tt++) {
    int cur = tt & 1, nxt = cur ^ 1;
    half8 vvn;
    if (tt < 15) {
      vvn = *(const half8*)(Vp + (size_t)vd * 1024 + (tt + 1) * 64 + vt);
      stage16(Kp + (size_t)((tt + 1) * 64 + kt_t) * 64 + kt_d, Ks[nxt] + w4 * 512, lane);
    }
    const _Float16* ks_ = Ks[cur];
    const _Float16* vs_ = Vs[cur];
    unsigned long long mw0 = __shfl(mq[0][tt & 3], ((tt >> 2) << 4) + la);
    unsigned long long mw1 = __shfl(mq[1][tt & 3], ((tt >> 2) << 4) + la);
#pragma unroll
    for (int tsub = 0; tsub < 4; tsub++) {
      half8 kf0 = *(const half8*)(ks_ + (tsub * 16 + la) * 32 + qd * 8);
      half8 kf1 = *(const half8*)(ks_ + 2048 + (tsub * 16 + la) * 32 + qd * 8);
      f32x4 a0 = {}, a1 = {};
      a0 = __builtin_amdgcn_mfma_f32_16x16x32_f16(kf0, qf[0][0], a0, 0, 0, 0);
      a1 = __builtin_amdgcn_mfma_f32_16x16x32_f16(kf0, qf[1][0], a1, 0, 0, 0);
      a0 = __builtin_amdgcn_mfma_f32_16x16x32_f16(kf1, qf[0][1], a0, 0, 0, 0);
      a1 = __builtin_amdgcn_mfma_f32_16x16x32_f16(kf1, qf[1][1], a1, 0, 0, 0);
      half4 pf[2];
#pragma unroll
      for (int qi = 0; qi < 2; qi++) {
        const f32x4& aa = qi ? a1 : a0;
        unsigned long long mw = qi ? mw1 : mw0;
        float e0 = ((mw >> (tsub * 16 + qd * 4 + 0)) & 1ull) ? EXP2(aa[0]) : 0.0f;
        float e1 = ((mw >> (tsub * 16 + qd * 4 + 1)) & 1ull) ? EXP2(aa[1]) : 0.0f;
        float e2 = ((mw >> (tsub * 16 + qd * 4 + 2)) & 1ull) ? EXP2(aa[2]) : 0.0f;
        float e3 = ((mw >> (tsub * 16 + qd * 4 + 3)) & 1ull) ? EXP2(aa[3]) : 0.0f;
#ifdef HAVE_PKRTZ
        fp16x2 p01 = __builtin_amdgcn_cvt_pkrtz(e0, e1);
        fp16x2 p23 = __builtin_amdgcn_cvt_pkrtz(e2, e3);
        fp16x4 pfv = __builtin_shufflevector(p01, p23, 0, 1, 2, 3);
        pf[qi] = __builtin_bit_cast(half4, pfv);
#else
        pf[qi][0] = (_Float16)e0; pf[qi][1] = (_Float16)e1;
        pf[qi][2] = (_Float16)e2; pf[qi][3] = (_Float16)e3;
#endif
#if defined(HAVE_FDOT2) && defined(HAVE_PKRTZ)
        rs[qi] = __builtin_amdgcn_fdot2(p01, one2, rs[qi], false);
        rs[qi] = __builtin_amdgcn_fdot2(p23, one2, rs[qi], false);
#else
        rs[qi] += e0 + e1 + e2 + e3;
#endif
      }
#pragma unroll
      for (int nsub = 0; nsub < 4; nsub++) {
        half4 vf = *(const half4*)(vs_ + (tsub >> 1) * 2560 + (nsub * 16 + la) * 40 +
                                   (tsub & 1) * 16 + qd * 4);
        acco[0][nsub] = __builtin_amdgcn_mfma_f32_16x16x16f16(pf[0], vf, acco[0][nsub], 0, 0, 0);
        acco[1][nsub] = __builtin_amdgcn_mfma_f32_16x16x16f16(pf[1], vf, acco[1][nsub], 0, 0, 0);
      }
    }
    if (tt < 15) *(half8*)(Vs[nxt] + vs_off) = vvn;
    __syncthreads();
  }
  float* op = out + (size_t)b * 1024 * 1024 + (size_t)h * 64;
#pragma unroll
  for (int qi = 0; qi < 2; qi++) {
    float r0 = rs[qi];
    r0 += __shfl_xor(r0, 16);
    r0 += __shfl_xor(r0, 32);
    float inv_q = 1.0f / (r0 + 1e-8f);
#pragma unroll
    for (int rg = 0; rg < 4; rg++) {
      float inv = __shfl(inv_q, qd * 4 + rg);
      int s = q0w + qi * 128 + qd * 4 + rg;
#pragma unroll
      for (int nsub = 0; nsub < 4; nsub++)
        op[(size_t)s * 1024 + nsub * 16 + la] = acco[qi][nsub][rg] * inv;
    }
  }
}

extern "C" void kernel_launch(void* const* d_in, const int* in_sizes, int n_in,
                              void* d_out, int out_size, void* d_ws, size_t ws_size,
                              hipStream_t stream) {
  (void)in_sizes; (void)n_in; (void)out_size; (void)ws_size;
  const float* x = (const float*)d_in[0];
  const float* am = (const float*)d_in[1];
  const float* Wq = (const float*)d_in[2];
  const float* Wk = (const float*)d_in[3];
  const float* Wv = (const float*)d_in[4];
  float* out = (float*)d_out;

  char* p = (char*)d_ws;
  _Float16* xb = (_Float16*)p;    p += (size_t)8192 * 1024 * 2;
  _Float16* Wqkvt = (_Float16*)p; p += (size_t)3 * 1024 * 1024 * 2;
  _Float16* Qt = (_Float16*)p;    p += (size_t)8192 * 1024 * 2;   // [b,h,d,s]
  _Float16* Kh = (_Float16*)p;    p += (size_t)8192 * 1024 * 2;   // [b,h,s,d]
  _Float16* Vth = (_Float16*)p;   p += (size_t)8192 * 1024 * 2;   // [b,h,d,s]
  unsigned long long* mb = (unsigned long long*)p;

  prep_kernel<<<44032, 256, 0, stream>>>(x, am, Wq, Wk, Wv, xb, Wqkvt, mb);
  gemm_kernel<<<dim3(384), 512, 0, stream>>>(xb, Wqkvt, Qt, Kh, Vth);
  attn_kernel<<<512, 512, 0, stream>>>(Qt, Kh, Vth, mb, out);
}

// Round 2
// 253.692 us; speedup vs baseline: 1.0286x; 1.0232x over previous
//
#include <hip/hip_runtime.h>

#define KDIM 1024

typedef _Float16 half8 __attribute__((ext_vector_type(8)));
typedef _Float16 half4 __attribute__((ext_vector_type(4)));
typedef __fp16 fp16x2 __attribute__((ext_vector_type(2)));
typedef __fp16 fp16x4 __attribute__((ext_vector_type(4)));
typedef float f32x4 __attribute__((ext_vector_type(4)));

#if defined(__has_builtin)
#if __has_builtin(__builtin_amdgcn_global_load_lds)
#define HAVE_GLDS 1
#endif
#if __has_builtin(__builtin_amdgcn_exp2f)
#define EXP2(x) __builtin_amdgcn_exp2f(x)
#endif
#if __has_builtin(__builtin_amdgcn_cvt_pkrtz)
#define HAVE_PKRTZ 1
#endif
#if __has_builtin(__builtin_amdgcn_fdot2)
#define HAVE_FDOT2 1
#endif
#endif
#ifndef EXP2
#define EXP2(x) exp2f(x)
#endif

__device__ __forceinline__ void stage16(const _Float16* g, _Float16* wave_base, int lane) {
#ifdef HAVE_GLDS
  __builtin_amdgcn_global_load_lds(
      (const __attribute__((address_space(1))) void*)g,
      (__attribute__((address_space(3))) void*)wave_base, 16, 0, 0);
#else
  *(half8*)(wave_base + lane * 8) = *(const half8*)g;
#endif
}

#define BARRIER() __builtin_amdgcn_s_barrier()
#define LGKM0()                                         \
  do {                                                  \
    asm volatile("s_waitcnt lgkmcnt(0)" ::: "memory");  \
    __builtin_amdgcn_sched_barrier(0);                  \
  } while (0)
#define VMCNT(n)                                               \
  do {                                                         \
    asm volatile("s_waitcnt vmcnt(" #n ")" ::: "memory");      \
  } while (0)

// ------------- merged prep: cast x | transpose-cast W | mask bits -------------
__global__ void prep_kernel(const float* __restrict__ x, const float* __restrict__ am,
                            const float* __restrict__ Wq, const float* __restrict__ Wk,
                            const float* __restrict__ Wv, _Float16* __restrict__ xb,
                            _Float16* __restrict__ Wqkvt, unsigned long long* __restrict__ bits) {
  __shared__ _Float16 tile[32][33];
  int bid = blockIdx.x;
  if (bid < 8192) {
    size_t i = ((size_t)bid * 256 + threadIdx.x) * 4;
    float4 v = *(const float4*)(x + i);
    half4 h = { (_Float16)v.x, (_Float16)v.y, (_Float16)v.z, (_Float16)v.w };
    *(half4*)(xb + i) = h;
  } else if (bid < 11264) {
    int zz = bid - 8192;
    int z = zz >> 10;
    int rem = zz & 1023;
    int bx = rem & 31, by = rem >> 5;
    const float* src = z == 0 ? Wq : (z == 1 ? Wk : Wv);
    _Float16* dst = Wqkvt + (size_t)z * KDIM * KDIM;
    float sc = (z == 0) ? 0.18033688011112042f : 1.0f;  // (1/8)*log2(e)
    int tx = threadIdx.x & 31, ty = threadIdx.x >> 5;
    int c0 = bx * 32, r0 = by * 32;
#pragma unroll
    for (int i = 0; i < 4; i++) {
      int r = r0 + ty + i * 8;
      tile[tx][ty + i * 8] = (_Float16)(src[(size_t)r * KDIM + c0 + tx] * sc);
    }
    __syncthreads();
#pragma unroll
    for (int i = 0; i < 4; i++) {
      int n = c0 + ty + i * 8;
      dst[(size_t)n * KDIM + r0 + tx] = tile[ty + i * 8][tx];
    }
  } else {
    size_t i = (size_t)(bid - 11264) * 256 + threadIdx.x;
    unsigned long long b = __ballot(am[i] != 0.0f);
    if ((threadIdx.x & 63) == 0) bits[i >> 6] = b;
  }
}

// ---------------- fused QKV GEMM, 256x256 tile, BK=64, 4-phase counted-vmcnt ----------------
// Schedule (per K-tile t; buffers cur=t&1, nxt=cur^1; stage order A1,B1,A0,B0):
//   ph1: read af(mh0)+bf0(nh0) [12 ds]; stage (t+1).A1->nxt; bar; lgkm0; MFMA(0,0); VMCNT(6); bar
//   ph2: read bf1(nh1) [4 ds];          stage (t+1).B1->nxt; bar; lgkm0; MFMA(0,1);           bar
//   ph3: read af(mh1) [8 ds];           stage (t+2).A0->cur; bar; lgkm0; MFMA(1,0);           bar
//   ph4:                                stage (t+2).B0->cur; bar;        MFMA(1,1); VMCNT(8); bar
// Counted waits sit BEFORE barriers (cross-wave handshake). Steady state keeps 3-4 half-tiles
// (6-8 loads) in flight; vmcnt never drains to 0 in the main loop.
__global__ __launch_bounds__(512, 2)
void gemm_kernel(const _Float16* __restrict__ A, const _Float16* __restrict__ Bt,
                 _Float16* __restrict__ Qt, _Float16* __restrict__ Kh,
                 _Float16* __restrict__ Vth) {
  __shared__ _Float16 As[2 * 16384];
  __shared__ _Float16 Bs[2 * 16384];
  int tid = threadIdx.x;
  int lane = tid & 63, w = tid >> 6;
  int la = lane & 15, qd = lane >> 4;
  int wm = w & 1, wn = w >> 1;  // 2M x 4N waves; wave tile 128x64 interleaved across halves
  // XCD-aware swizzle: 384 blocks, 48 consecutive wgs per XCD (384 % 8 == 0 -> bijective)
  int bid = blockIdx.x;
  int wg = (bid & 7) * 48 + (bid >> 3);
  int by = wg / 12, bx = wg - by * 12;
  int m0 = by * 256, n0 = bx * 256;
  // staging geometry: thread -> row (tid>>3) + 64*l, 16B chunk (tid&7); source pre-swizzled
  int srow = tid >> 3;
  int scc = ((srow & 7) ^ (tid & 7)) << 3;  // pre-swizzled source chunk (halves)
  // read-side swizzled chunk offsets for k=0/k=1 (halves)
  const int rc0 = ((qd ^ (la & 7)) << 3);
  const int rc1 = (((4 | qd) ^ (la & 7)) << 3);

  const _Float16* Ab = A + (size_t)m0 * KDIM;
  const _Float16* Bb = Bt + (size_t)n0 * KDIM;

  // per-lane global staging pointers (bumped +64 halves per use)
  const _Float16* pA0a = Ab + (size_t)(srow) * KDIM + scc;
  const _Float16* pA0b = Ab + (size_t)(srow + 64) * KDIM + scc;
  const _Float16* pA1a = Ab + (size_t)(srow + 128) * KDIM + scc;
  const _Float16* pA1b = Ab + (size_t)(srow + 192) * KDIM + scc;
  const _Float16* pB0a = Bb + (size_t)(srow) * KDIM + scc;
  const _Float16* pB0b = Bb + (size_t)(srow + 64) * KDIM + scc;
  const _Float16* pB1a = Bb + (size_t)(srow + 128) * KDIM + scc;
  const _Float16* pB1b = Bb + (size_t)(srow + 192) * KDIM + scc;

  // wave-uniform LDS staging bases
  _Float16* ldsAw = As + w * 512;
  _Float16* ldsBw = Bs + w * 512;

  // per-lane LDS read bases (all loop offsets are compile-time immediates)
  const _Float16* baseA0 = As + wm * 4096 + la * 64 + rc0;
  const _Float16* baseA1 = As + wm * 4096 + la * 64 + rc1;
  const _Float16* baseB0 = Bs + wn * 2048 + la * 64 + rc0;
  const _Float16* baseB1 = Bs + wn * 2048 + la * 64 + rc1;

  f32x4 acc[8][4] = {};
  half8 af[4][2], bf0[2][2], bf1[2][2];

#define STAGE_A1(NXT)                                              \
  do {                                                             \
    stage16(pA1a, ldsAw + (NXT) * 16384 + 8192, lane);             \
    stage16(pA1b, ldsAw + (NXT) * 16384 + 8192 + 4096, lane);      \
    pA1a += 64; pA1b += 64;                                        \
  } while (0)
#define STAGE_B1(NXT)                                              \
  do {                                                             \
    stage16(pB1a, ldsBw + (NXT) * 16384 + 8192, lane);             \
    stage16(pB1b, ldsBw + (NXT) * 16384 + 8192 + 4096, lane);      \
    pB1a += 64; pB1b += 64;                                        \
  } while (0)
#define STAGE_A0(CUR)                                              \
  do {                                                             \
    stage16(pA0a, ldsAw + (CUR) * 16384, lane);                    \
    stage16(pA0b, ldsAw + (CUR) * 16384 + 4096, lane);             \
    pA0a += 64; pA0b += 64;                                        \
  } while (0)
#define STAGE_B0(CUR)                                              \
  do {                                                             \
    stage16(pB0a, ldsBw + (CUR) * 16384, lane);                    \
    stage16(pB0b, ldsBw + (CUR) * 16384 + 4096, lane);             \
    pB0a += 64; pB0b += 64;                                        \
  } while (0)
#define LD_AF(CUR, MH)                                                              \
  do {                                                                              \
    _Pragma("unroll") for (int mi = 0; mi < 4; ++mi) {                              \
      af[mi][0] = *(const half8*)(baseA0 + (CUR) * 16384 + (MH) * 8192 + mi * 1024); \
      af[mi][1] = *(const half8*)(baseA1 + (CUR) * 16384 + (MH) * 8192 + mi * 1024); \
    }                                                                               \
  } while (0)
#define LD_BF(BF, CUR, NH)                                                          \
  do {                                                                              \
    _Pragma("unroll") for (int nj = 0; nj < 2; ++nj) {                              \
      BF[nj][0] = *(const half8*)(baseB0 + (CUR) * 16384 + (NH) * 8192 + nj * 1024); \
      BF[nj][1] = *(const half8*)(baseB1 + (CUR) * 16384 + (NH) * 8192 + nj * 1024); \
    }                                                                               \
  } while (0)
#define MFMA_Q(MH, NH, BF)                                                          \
  do {                                                                              \
    __builtin_amdgcn_s_setprio(1);                                                  \
    _Pragma("unroll") for (int mi = 0; mi < 4; ++mi)                                \
        _Pragma("unroll") for (int nj = 0; nj < 2; ++nj) {                          \
      acc[(MH) * 4 + mi][(NH) * 2 + nj] = __builtin_amdgcn_mfma_f32_16x16x32_f16(   \
          af[mi][0], BF[nj][0], acc[(MH) * 4 + mi][(NH) * 2 + nj], 0, 0, 0);        \
      acc[(MH) * 4 + mi][(NH) * 2 + nj] = __builtin_amdgcn_mfma_f32_16x16x32_f16(   \
          af[mi][1], BF[nj][1], acc[(MH) * 4 + mi][(NH) * 2 + nj], 0, 0, 0);        \
    }                                                                               \
    __builtin_amdgcn_s_setprio(0);                                                  \
  } while (0)

  // Prologue stage order (q): A0(0),B0(0),A1(0),B1(0),A0(1),B0(1) — 12 loads.
  stage16(pA0a, ldsAw, lane);
  stage16(pA0b, ldsAw + 4096, lane);
  stage16(pB0a, ldsBw, lane);
  stage16(pB0b, ldsBw + 4096, lane);
  stage16(pA1a, ldsAw + 8192, lane);
  stage16(pA1b, ldsAw + 8192 + 4096, lane);
  stage16(pB1a, ldsBw + 8192, lane);
  stage16(pB1b, ldsBw + 8192 + 4096, lane);
  stage16(pA0a + 64, ldsAw + 16384, lane);
  stage16(pA0b + 64, ldsAw + 16384 + 4096, lane);
  stage16(pB0a + 64, ldsBw + 16384, lane);
  stage16(pB0b + 64, ldsBw + 16384 + 4096, lane);
  pA0a += 128; pA0b += 128; pB0a += 128; pB0b += 128;
  pA1a += 64;  pA1b += 64;  pB1a += 64;  pB1b += 64;
  VMCNT(8);
  BARRIER();

#define KTILE(T, CUR, NXT)                                     \
  do {                                                         \
    int t = (T);                                               \
    /* phase 1 */                                              \
    LD_AF(CUR, 0);                                             \
    LD_BF(bf0, CUR, 0);                                        \
    if (t < 15) STAGE_A1(NXT);                                 \
    BARRIER();                                                 \
    LGKM0();                                                   \
    MFMA_Q(0, 0, bf0);                                         \
    if (t < 15) { VMCNT(6); } else { VMCNT(0); }               \
    BARRIER();                                                 \
    /* phase 2 */                                              \
    LD_BF(bf1, CUR, 1);                                        \
    if (t < 15) STAGE_B1(NXT);                                 \
    BARRIER();                                                 \
    LGKM0();                                                   \
    MFMA_Q(0, 1, bf1);                                         \
    BARRIER();                                                 \
    /* phase 3 */                                              \
    LD_AF(CUR, 1);                                             \
    if (t < 14) STAGE_A0(CUR);                                 \
    BARRIER();                                                 \
    LGKM0();                                                   \
    MFMA_Q(1, 0, bf0);                                         \
    BARRIER();                                                 \
    /* phase 4 */                                              \
    if (t < 14) STAGE_B0(CUR);                                 \
    BARRIER();                                                 \
    MFMA_Q(1, 1, bf1);                                         \
    if (t < 14) { VMCNT(8); } else if (t == 14) { VMCNT(4); }  \
    BARRIER();                                                 \
  } while (0)

#pragma unroll 1
  for (int tp = 0; tp < 8; ++tp) {
    KTILE(2 * tp, 0, 1);
    KTILE(2 * tp + 1, 1, 0);
  }

#undef KTILE
#undef MFMA_Q
#undef LD_BF
#undef LD_AF
#undef STAGE_B0
#undef STAGE_A0
#undef STAGE_B1
#undef STAGE_A1

  // ---------------- epilogue ----------------
  int which = n0 >> 10;  // 0:Q 1:K 2:V (uniform per block; 1024 % 256 == 0)
  int n0k = n0 & 1023;
  if (which == 1) {
#pragma unroll
    for (int mh = 0; mh < 2; ++mh) {
      int srow0 = m0 + mh * 128 + wm * 64;
      int b = srow0 >> 10, s0 = srow0 & 1023;
#pragma unroll
      for (int nh = 0; nh < 2; ++nh)
#pragma unroll
        for (int nj = 0; nj < 2; ++nj) {
          int colh = n0k + nh * 128 + wn * 32 + nj * 16;
          int hh = colh >> 6;
          int d = (colh & 63) + la;
          _Float16* kb = Kh + (size_t)(b * 16 + hh) * 1024 * 64;
#pragma unroll
          for (int mi = 0; mi < 4; ++mi) {
            f32x4 v = acc[mh * 4 + mi][nh * 2 + nj];
            int s = s0 + mi * 16 + qd * 4;
#pragma unroll
            for (int rg = 0; rg < 4; ++rg)
              kb[(size_t)(s + rg) * 64 + d] = (_Float16)v[rg];
          }
        }
    }
  } else {
    _Float16* dst = (which == 0) ? Qt : Vth;
    // wave-private 16x72 transpose patch in As (all waves past final barrier)
    _Float16* ep = As + w * 1280;
    int rr = lane >> 2, c4 = lane & 3;
#pragma unroll
    for (int mh = 0; mh < 2; ++mh) {
      int srow0 = m0 + mh * 128 + wm * 64;
      int b = srow0 >> 10, s0 = srow0 & 1023;
#pragma unroll
      for (int nh = 0; nh < 2; ++nh)
#pragma unroll
        for (int nj = 0; nj < 2; ++nj) {
          int colh = n0k + nh * 128 + wn * 32 + nj * 16;
          int hh = colh >> 6, d0 = colh & 63;
#pragma unroll
          for (int mi = 0; mi < 4; ++mi) {
            f32x4 v = acc[mh * 4 + mi][nh * 2 + nj];
            half4 hv = { (_Float16)v[0], (_Float16)v[1], (_Float16)v[2], (_Float16)v[3] };
            *(half4*)(ep + la * 72 + mi * 16 + qd * 4) = hv;  // row=d(la), col=s
          }
          half8 o0 = *(const half8*)(ep + rr * 72 + c4 * 16);
          half8 o1 = *(const half8*)(ep + rr * 72 + c4 * 16 + 8);
          _Float16* gp = dst + ((size_t)(b * 16 + hh) * 64 + d0 + rr) * 1024 + s0 + c4 * 16;
          *(half8*)gp = o0;
          *(half8*)(gp + 8) = o1;
        }
    }
  }
}

// ---------------- fused attention (unchanged) ----------------
__global__ __launch_bounds__(512, 2)
void attn_kernel(const _Float16* __restrict__ Qt, const _Float16* __restrict__ K,
                 const _Float16* __restrict__ Vt, const unsigned long long* __restrict__ mbits,
                 float* __restrict__ out) {
  __shared__ _Float16 Ks[2][2 * 64 * 32];  // [buf][ks=d/32][t][32]
  __shared__ _Float16 Vs[2][2 * 64 * 40];  // [buf][tc=t/32][d][40 padded]
  int tid = threadIdx.x;
  int lane = tid & 63, w4 = tid >> 6;  // w4 0..7
  int la = lane & 15, qd = lane >> 4;
  int linear = blockIdx.x;
  int xlo = linear & 7;
  int tmp = linear >> 3;  // 0..63
  int qt = tmp & 3;
  int hb = (tmp >> 2) * 8 + xlo;  // 0..127
  int h = hb & 15, b = hb >> 4;
  const _Float16* Qp = Qt + (size_t)hb * 64 * 1024;  // [d][s]
  const _Float16* Kp = K + (size_t)hb * 1024 * 64;   // [s][d]
  const _Float16* Vp = Vt + (size_t)hb * 64 * 1024;  // [d][s]
  int q0w = qt * 256 + w4 * 16;  // qfrag qi adds qi*128
  half8 qf[2][2];
#pragma unroll
  for (int qi = 0; qi < 2; qi++)
#pragma unroll
    for (int ks = 0; ks < 2; ks++)
#pragma unroll
      for (int j = 0; j < 8; j++)
        qf[qi][ks][j] = Qp[(size_t)(ks * 32 + qd * 8 + j) * 1024 + q0w + qi * 128 + la];
  unsigned long long mq[2][4];
#pragma unroll
  for (int qi = 0; qi < 2; qi++) {
    const ulonglong2* mp =
        (const ulonglong2*)(mbits + ((size_t)b * 1024 + q0w + qi * 128 + la) * 16 + qd * 4);
    ulonglong2 m01 = mp[0];
    ulonglong2 m23 = mp[1];
    mq[qi][0] = m01.x; mq[qi][1] = m01.y; mq[qi][2] = m23.x; mq[qi][3] = m23.y;
  }
  f32x4 acco[2][4] = {};
  float rs[2] = {0.f, 0.f};
  int kt_t = (tid & 255) >> 2;
  int kt_d = (tid >> 8) * 32 + (tid & 3) * 8;
  int vd = tid >> 3;
  int vt = (tid & 7) * 8;
  int vs_off = (vt >= 32 ? 2560 : 0) + vd * 40 + (vt & 31);
#if defined(HAVE_FDOT2) && defined(HAVE_PKRTZ)
  fp16x2 one2 = { (__fp16)1.0f, (__fp16)1.0f };
#endif
  {
    stage16(Kp + (size_t)kt_t * 64 + kt_d, Ks[0] + w4 * 512, lane);
    half8 vv = *(const half8*)(Vp + (size_t)vd * 1024 + vt);
    *(half8*)(Vs[0] + vs_off) = vv;
  }
  __syncthreads();
  for (int tt = 0; tt < 16; tt++) {
    int cur = tt & 1, nxt = cur ^ 1;
    half8 vvn;
    if (tt < 15) {
      vvn = *(const half8*)(Vp + (size_t)vd * 1024 + (tt + 1) * 64 + vt);
      stage16(Kp + (size_t)((tt + 1) * 64 + kt_t) * 64 + kt_d, Ks[nxt] + w4 * 512, lane);
    }
    const _Float16* ks_ = Ks[cur];
    const _Float16* vs_ = Vs[cur];
    unsigned long long mw0 = __shfl(mq[0][tt & 3], ((tt >> 2) << 4) + la);
    unsigned long long mw1 = __shfl(mq[1][tt & 3], ((tt >> 2) << 4) + la);
#pragma unroll
    for (int tsub = 0; tsub < 4; tsub++) {
      half8 kf0 = *(const half8*)(ks_ + (tsub * 16 + la) * 32 + qd * 8);
      half8 kf1 = *(const half8*)(ks_ + 2048 + (tsub * 16 + la) * 32 + qd * 8);
      f32x4 a0 = {}, a1 = {};
      a0 = __builtin_amdgcn_mfma_f32_16x16x32_f16(kf0, qf[0][0], a0, 0, 0, 0);
      a1 = __builtin_amdgcn_mfma_f32_16x16x32_f16(kf0, qf[1][0], a1, 0, 0, 0);
      a0 = __builtin_amdgcn_mfma_f32_16x16x32_f16(kf1, qf[0][1], a0, 0, 0, 0);
      a1 = __builtin_amdgcn_mfma_f32_16x16x32_f16(kf1, qf[1][1], a1, 0, 0, 0);
      half4 pf[2];
#pragma unroll
      for (int qi = 0; qi < 2; qi++) {
        const f32x4& aa = qi ? a1 : a0;
        unsigned long long mw = qi ? mw1 : mw0;
        float e0 = ((mw >> (tsub * 16 + qd * 4 + 0)) & 1ull) ? EXP2(aa[0]) : 0.0f;
        float e1 = ((mw >> (tsub * 16 + qd * 4 + 1)) & 1ull) ? EXP2(aa[1]) : 0.0f;
        float e2 = ((mw >> (tsub * 16 + qd * 4 + 2)) & 1ull) ? EXP2(aa[2]) : 0.0f;
        float e3 = ((mw >> (tsub * 16 + qd * 4 + 3)) & 1ull) ? EXP2(aa[3]) : 0.0f;
#ifdef HAVE_PKRTZ
        fp16x2 p01 = __builtin_amdgcn_cvt_pkrtz(e0, e1);
        fp16x2 p23 = __builtin_amdgcn_cvt_pkrtz(e2, e3);
        fp16x4 pfv = __builtin_shufflevector(p01, p23, 0, 1, 2, 3);
        pf[qi] = __builtin_bit_cast(half4, pfv);
#else
        pf[qi][0] = (_Float16)e0; pf[qi][1] = (_Float16)e1;
        pf[qi][2] = (_Float16)e2; pf[qi][3] = (_Float16)e3;
#endif
#if defined(HAVE_FDOT2) && defined(HAVE_PKRTZ)
        rs[qi] = __builtin_amdgcn_fdot2(p01, one2, rs[qi], false);
        rs[qi] = __builtin_amdgcn_fdot2(p23, one2, rs[qi], false);
#else
        rs[qi] += e0 + e1 + e2 + e3;
#endif
      }
#pragma unroll
      for (int nsub = 0; nsub < 4; nsub++) {
        half4 vf = *(const half4*)(vs_ + (tsub >> 1) * 2560 + (nsub * 16 + la) * 40 +
                                   (tsub & 1) * 16 + qd * 4);
        acco[0][nsub] = __builtin_amdgcn_mfma_f32_16x16x16f16(pf[0], vf, acco[0][nsub], 0, 0, 0);
        acco[1][nsub] = __builtin_amdgcn_mfma_f32_16x16x16f16(pf[1], vf, acco[1][nsub], 0, 0, 0);
      }
    }
    if (tt < 15) *(half8*)(Vs[nxt] + vs_off) = vvn;
    __syncthreads();
  }
  float* op = out + (size_t)b * 1024 * 1024 + (size_t)h * 64;
#pragma unroll
  for (int qi = 0; qi < 2; qi++) {
    float r0 = rs[qi];
    r0 += __shfl_xor(r0, 16);
    r0 += __shfl_xor(r0, 32);
    float inv_q = 1.0f / (r0 + 1e-8f);
#pragma unroll
    for (int rg = 0; rg < 4; rg++) {
      float inv = __shfl(inv_q, qd * 4 + rg);
      int s = q0w + qi * 128 + qd * 4 + rg;
#pragma unroll
      for (int nsub = 0; nsub < 4; nsub++)
        op[(size_t)s * 1024 + nsub * 16 + la] = acco[qi][nsub][rg] * inv;
    }
  }
}

extern "C" void kernel_launch(void* const* d_in, const int* in_sizes, int n_in,
                              void* d_out, int out_size, void* d_ws, size_t ws_size,
                              hipStream_t stream) {
  (void)in_sizes; (void)n_in; (void)out_size; (void)ws_size;
  const float* x = (const float*)d_in[0];
  const float* am = (const float*)d_in[1];
  const float* Wq = (const float*)d_in[2];
  const float* Wk = (const float*)d_in[3];
  const float* Wv = (const float*)d_in[4];
  float* out = (float*)d_out;

  char* p = (char*)d_ws;
  _Float16* xb = (_Float16*)p;    p += (size_t)8192 * 1024 * 2;
  _Float16* Wqkvt = (_Float16*)p; p += (size_t)3 * 1024 * 1024 * 2;
  _Float16* Qt = (_Float16*)p;    p += (size_t)8192 * 1024 * 2;   // [b,h,d,s]
  _Float16* Kh = (_Float16*)p;    p += (size_t)8192 * 1024 * 2;   // [b,h,s,d]
  _Float16* Vth = (_Float16*)p;   p += (size_t)8192 * 1024 * 2;   // [b,h,d,s]
  unsigned long long* mb = (unsigned long long*)p;

  prep_kernel<<<44032, 256, 0, stream>>>(x, am, Wq, Wk, Wv, xb, Wqkvt, mb);
  gemm_kernel<<<dim3(384), 512, 0, stream>>>(xb, Wqkvt, Qt, Kh, Vth);
  attn_kernel<<<512, 512, 0, stream>>>(Qt, Kh, Vth, mb, out);
}

// Round 3
// 249.845 us; speedup vs baseline: 1.0444x; 1.0154x over previous
//
#include <hip/hip_runtime.h>

#define KDIM 1024

typedef _Float16 half8 __attribute__((ext_vector_type(8)));
typedef _Float16 half4 __attribute__((ext_vector_type(4)));
typedef __fp16 fp16x2 __attribute__((ext_vector_type(2)));
typedef __fp16 fp16x4 __attribute__((ext_vector_type(4)));
typedef float f32x4 __attribute__((ext_vector_type(4)));

#if defined(__has_builtin)
#if __has_builtin(__builtin_amdgcn_global_load_lds)
#define HAVE_GLDS 1
#endif
#if __has_builtin(__builtin_amdgcn_exp2f)
#define EXP2(x) __builtin_amdgcn_exp2f(x)
#endif
#if __has_builtin(__builtin_amdgcn_cvt_pkrtz)
#define HAVE_PKRTZ 1
#endif
#if __has_builtin(__builtin_amdgcn_fdot2)
#define HAVE_FDOT2 1
#endif
#endif
#ifndef EXP2
#define EXP2(x) exp2f(x)
#endif

__device__ __forceinline__ void stage16(const _Float16* g, _Float16* wave_base, int lane) {
#ifdef HAVE_GLDS
  __builtin_amdgcn_global_load_lds(
      (const __attribute__((address_space(1))) void*)g,
      (__attribute__((address_space(3))) void*)wave_base, 16, 0, 0);
#else
  *(half8*)(wave_base + lane * 8) = *(const half8*)g;
#endif
}

#define BARRIER() __builtin_amdgcn_s_barrier()
#define LGKM0()                                         \
  do {                                                  \
    asm volatile("s_waitcnt lgkmcnt(0)" ::: "memory");  \
    __builtin_amdgcn_sched_barrier(0);                  \
  } while (0)
#define VMCNT(n)                                               \
  do {                                                         \
    asm volatile("s_waitcnt vmcnt(" #n ")" ::: "memory");      \
  } while (0)

// ------------- merged prep: cast x | transpose-cast W | mask bits -------------
__global__ void prep_kernel(const float* __restrict__ x, const float* __restrict__ am,
                            const float* __restrict__ Wq, const float* __restrict__ Wk,
                            const float* __restrict__ Wv, _Float16* __restrict__ xb,
                            _Float16* __restrict__ Wqkvt, unsigned long long* __restrict__ bits) {
  __shared__ _Float16 tile[32][33];
  int bid = blockIdx.x;
  if (bid < 8192) {
    size_t i = ((size_t)bid * 256 + threadIdx.x) * 4;
    float4 v = *(const float4*)(x + i);
    half4 h = { (_Float16)v.x, (_Float16)v.y, (_Float16)v.z, (_Float16)v.w };
    *(half4*)(xb + i) = h;
  } else if (bid < 11264) {
    int zz = bid - 8192;
    int z = zz >> 10;
    int rem = zz & 1023;
    int bx = rem & 31, by = rem >> 5;
    const float* src = z == 0 ? Wq : (z == 1 ? Wk : Wv);
    _Float16* dst = Wqkvt + (size_t)z * KDIM * KDIM;
    float sc = (z == 0) ? 0.18033688011112042f : 1.0f;  // (1/8)*log2(e)
    int tx = threadIdx.x & 31, ty = threadIdx.x >> 5;
    int c0 = bx * 32, r0 = by * 32;
#pragma unroll
    for (int i = 0; i < 4; i++) {
      int r = r0 + ty + i * 8;
      tile[tx][ty + i * 8] = (_Float16)(src[(size_t)r * KDIM + c0 + tx] * sc);
    }
    __syncthreads();
#pragma unroll
    for (int i = 0; i < 4; i++) {
      int n = c0 + ty + i * 8;
      dst[(size_t)n * KDIM + r0 + tx] = tile[ty + i * 8][tx];
    }
  } else {
    size_t i = (size_t)(bid - 11264) * 256 + threadIdx.x;
    unsigned long long b = __ballot(am[i] != 0.0f);
    if ((threadIdx.x & 63) == 0) bits[i >> 6] = b;
  }
}

// ---------------- fused QKV GEMM, 256x192 tile, BK=64, 3-phase counted-vmcnt ----------------
// Grid 32x16 = 512 blocks = exactly 2 rounds on 256 CUs (no partial tail).
// Per tile t (cur=t&1): thirds B0/B1/B2 (64 rows each); A halves A0/A1 (128 rows).
//   ph1: read af(mh0)[8] + bf0[2]; stage (t+1).{A0[2],B0[1]}->nxt; bar; lgkm0; MFMA(mh0,n0)=8;
//        vmcnt(3) [retires old A1,B1,B2 -> ph2/ph3 reads safe]; bar
//   ph2: read bf1[2]+bf2[2]; stage (t+1).A1[2]->nxt; bar; lgkm0; MFMA(mh0,n1+n2)=16; bar
//   ph3: read af(mh1)[8]; stage (t+1).{B1,B2}[2]->nxt; bar; lgkm0; MFMA(mh1,n0..n2)=24;
//        vmcnt(4) [retires (t+1).A0,B0 -> next ph1 reads safe]; bar
__global__ __launch_bounds__(512, 2)
void gemm_kernel(const _Float16* __restrict__ A, const _Float16* __restrict__ Bt,
                 _Float16* __restrict__ Qt, _Float16* __restrict__ Kh,
                 _Float16* __restrict__ Vth) {
  __shared__ _Float16 As[2 * 16384];   // [buf][256 rows][64]
  __shared__ _Float16 Bs[2 * 12288];   // [buf][192 rows][64]
  int tid = threadIdx.x;
  int lane = tid & 63, w = tid >> 6;
  int la = lane & 15, qd = lane >> 4;
  int wm = w & 1, wn = w >> 1;  // 2M x 4N waves; per-wave out 128 x 48 (3 n-frags strided 64)
  // XCD swizzle: 512 blocks, 64 consecutive wgs per XCD (512 % 8 == 0 -> bijective)
  int bid = blockIdx.x;
  int wg = (bid & 7) * 64 + (bid >> 3);
  int by = wg >> 4, bx = wg & 15;
  int m0 = by * 256, n0 = bx * 192;
  int srow = tid >> 3;
  int scc = ((srow & 7) ^ (tid & 7)) << 3;  // pre-swizzled source chunk (halves)
  const int rc0 = ((qd ^ (la & 7)) << 3);
  const int rc1 = (((4 | qd) ^ (la & 7)) << 3);

  const _Float16* Ab = A + (size_t)m0 * KDIM;
  const _Float16* Bb = Bt + (size_t)n0 * KDIM;

  // per-lane global staging pointers (bumped +64 halves per tile)
  const _Float16* pA0a = Ab + (size_t)(srow) * KDIM + scc;
  const _Float16* pA0b = Ab + (size_t)(srow + 64) * KDIM + scc;
  const _Float16* pA1a = Ab + (size_t)(srow + 128) * KDIM + scc;
  const _Float16* pA1b = Ab + (size_t)(srow + 192) * KDIM + scc;
  const _Float16* pB0 = Bb + (size_t)(srow) * KDIM + scc;
  const _Float16* pB1 = Bb + (size_t)(srow + 64) * KDIM + scc;
  const _Float16* pB2 = Bb + (size_t)(srow + 128) * KDIM + scc;

  _Float16* ldsAw = As + w * 512;
  _Float16* ldsBw = Bs + w * 512;

  const _Float16* baseA0 = As + wm * 4096 + la * 64 + rc0;
  const _Float16* baseA1 = As + wm * 4096 + la * 64 + rc1;
  const _Float16* baseB0 = Bs + (wn * 16 + la) * 64 + rc0;
  const _Float16* baseB1 = Bs + (wn * 16 + la) * 64 + rc1;

  f32x4 acc[8][3] = {};
  half8 af[4][2], bf0[2], bf1[2], bf2[2];

#define STAGE_A0(B)                                       \
  do {                                                    \
    stage16(pA0a, ldsAw + (B) * 16384, lane);             \
    stage16(pA0b, ldsAw + (B) * 16384 + 4096, lane);      \
    pA0a += 64; pA0b += 64;                               \
  } while (0)
#define STAGE_A1(B)                                       \
  do {                                                    \
    stage16(pA1a, ldsAw + (B) * 16384 + 8192, lane);      \
    stage16(pA1b, ldsAw + (B) * 16384 + 12288, lane);     \
    pA1a += 64; pA1b += 64;                               \
  } while (0)
#define STAGE_B0(B)                                       \
  do { stage16(pB0, ldsBw + (B) * 12288, lane); pB0 += 64; } while (0)
#define STAGE_B1(B)                                       \
  do { stage16(pB1, ldsBw + (B) * 12288 + 4096, lane); pB1 += 64; } while (0)
#define STAGE_B2(B)                                       \
  do { stage16(pB2, ldsBw + (B) * 12288 + 8192, lane); pB2 += 64; } while (0)
#define LD_AF(CUR, MH)                                                               \
  do {                                                                               \
    _Pragma("unroll") for (int mi = 0; mi < 4; ++mi) {                               \
      af[mi][0] = *(const half8*)(baseA0 + (CUR) * 16384 + (MH) * 8192 + mi * 1024); \
      af[mi][1] = *(const half8*)(baseA1 + (CUR) * 16384 + (MH) * 8192 + mi * 1024); \
    }                                                                                \
  } while (0)
#define LD_B(BF, CUR, NJ)                                                  \
  do {                                                                     \
    BF[0] = *(const half8*)(baseB0 + (CUR) * 12288 + (NJ) * 4096);         \
    BF[1] = *(const half8*)(baseB1 + (CUR) * 12288 + (NJ) * 4096);         \
  } while (0)
#define MFMA_N(MH, NJ, BF)                                                          \
  do {                                                                              \
    _Pragma("unroll") for (int mi = 0; mi < 4; ++mi) {                              \
      acc[(MH) * 4 + mi][NJ] = __builtin_amdgcn_mfma_f32_16x16x32_f16(              \
          af[mi][0], BF[0], acc[(MH) * 4 + mi][NJ], 0, 0, 0);                       \
      acc[(MH) * 4 + mi][NJ] = __builtin_amdgcn_mfma_f32_16x16x32_f16(              \
          af[mi][1], BF[1], acc[(MH) * 4 + mi][NJ], 0, 0, 0);                       \
    }                                                                               \
  } while (0)

  // Prologue: tile0 fully (7 loads), drain, barrier.
  STAGE_A0(0); STAGE_B0(0); STAGE_A1(0); STAGE_B1(0); STAGE_B2(0);
  VMCNT(0);
  BARRIER();

#define KTILE(T, CUR, NXT)                                     \
  do {                                                         \
    int t = (T);                                               \
    /* phase 1 */                                              \
    LD_AF(CUR, 0);                                             \
    LD_B(bf0, CUR, 0);                                         \
    if (t < 15) { STAGE_A0(NXT); STAGE_B0(NXT); }              \
    BARRIER();                                                 \
    LGKM0();                                                   \
    __builtin_amdgcn_s_setprio(1);                             \
    MFMA_N(0, 0, bf0);                                         \
    __builtin_amdgcn_s_setprio(0);                             \
    if (t < 15) { VMCNT(3); } else { VMCNT(0); }               \
    BARRIER();                                                 \
    /* phase 2 */                                              \
    LD_B(bf1, CUR, 1);                                         \
    LD_B(bf2, CUR, 2);                                         \
    if (t < 15) STAGE_A1(NXT);                                 \
    BARRIER();                                                 \
    LGKM0();                                                   \
    __builtin_amdgcn_s_setprio(1);                             \
    MFMA_N(0, 1, bf1);                                         \
    MFMA_N(0, 2, bf2);                                         \
    __builtin_amdgcn_s_setprio(0);                             \
    BARRIER();                                                 \
    /* phase 3 */                                              \
    LD_AF(CUR, 1);                                             \
    if (t < 15) { STAGE_B1(NXT); STAGE_B2(NXT); }              \
    BARRIER();                                                 \
    LGKM0();                                                   \
    __builtin_amdgcn_s_setprio(1);                             \
    MFMA_N(1, 0, bf0);                                         \
    MFMA_N(1, 1, bf1);                                         \
    MFMA_N(1, 2, bf2);                                         \
    __builtin_amdgcn_s_setprio(0);                             \
    if (t < 15) { VMCNT(4); }                                  \
    BARRIER();                                                 \
  } while (0)

#pragma unroll 1
  for (int tp = 0; tp < 8; ++tp) {
    KTILE(2 * tp, 0, 1);
    KTILE(2 * tp + 1, 1, 0);
  }

#undef KTILE
#undef MFMA_N
#undef LD_B
#undef LD_AF
#undef STAGE_B2
#undef STAGE_B1
#undef STAGE_B0
#undef STAGE_A1
#undef STAGE_A0

  // ---------------- epilogue (per-frag Q/K/V routing: 192-col tiles span matrices) ----------
  int rr = lane >> 2, c4 = lane & 3;
  _Float16* ep = As + w * 1280;  // wave-private 16x72 transpose patch
#pragma unroll
  for (int mh = 0; mh < 2; ++mh) {
    int srow0 = m0 + mh * 128 + wm * 64;
    int b = srow0 >> 10, s0 = srow0 & 1023;
#pragma unroll
    for (int nj = 0; nj < 3; ++nj) {
      int colh = n0 + wn * 16 + nj * 64;
      int whichf = colh >> 10;       // 0:Q 1:K 2:V (uniform per wave,nj)
      int cm = colh & 1023;
      int hh = cm >> 6, d0 = cm & 63;
      if (whichf == 1) {
        _Float16* kb = Kh + (size_t)(b * 16 + hh) * 1024 * 64;
#pragma unroll
        for (int mi = 0; mi < 4; ++mi) {
          f32x4 v = acc[mh * 4 + mi][nj];
          int s = s0 + mi * 16 + qd * 4;
#pragma unroll
          for (int rg = 0; rg < 4; ++rg)
            kb[(size_t)(s + rg) * 64 + d0 + la] = (_Float16)v[rg];
        }
      } else {
        _Float16* dst = (whichf == 0) ? Qt : Vth;
#pragma unroll
        for (int mi = 0; mi < 4; ++mi) {
          f32x4 v = acc[mh * 4 + mi][nj];
          half4 hv = { (_Float16)v[0], (_Float16)v[1], (_Float16)v[2], (_Float16)v[3] };
          *(half4*)(ep + la * 72 + mi * 16 + qd * 4) = hv;  // row=d(la), col=s
        }
        half8 o0 = *(const half8*)(ep + rr * 72 + c4 * 16);
        half8 o1 = *(const half8*)(ep + rr * 72 + c4 * 16 + 8);
        _Float16* gp = dst + ((size_t)(b * 16 + hh) * 64 + d0 + rr) * 1024 + s0 + c4 * 16;
        *(half8*)gp = o0;
        *(half8*)(gp + 8) = o1;
      }
    }
  }
}

// ---------------- fused attention (K-LDS XOR swizzle added) ----------------
__global__ __launch_bounds__(512, 2)
void attn_kernel(const _Float16* __restrict__ Qt, const _Float16* __restrict__ K,
                 const _Float16* __restrict__ Vt, const unsigned long long* __restrict__ mbits,
                 float* __restrict__ out) {
  __shared__ _Float16 Ks[2][2 * 64 * 32];  // [buf][ks=d/32][t][32], 16B-chunk XOR-swizzled
  __shared__ _Float16 Vs[2][2 * 64 * 40];  // [buf][tc=t/32][d][40 padded]
  int tid = threadIdx.x;
  int lane = tid & 63, w4 = tid >> 6;  // w4 0..7
  int la = lane & 15, qd = lane >> 4;
  int linear = blockIdx.x;
  int xlo = linear & 7;
  int tmp = linear >> 3;  // 0..63
  int qt = tmp & 3;
  int hb = (tmp >> 2) * 8 + xlo;  // 0..127
  int h = hb & 15, b = hb >> 4;
  const _Float16* Qp = Qt + (size_t)hb * 64 * 1024;  // [d][s]
  const _Float16* Kp = K + (size_t)hb * 1024 * 64;   // [s][d]
  const _Float16* Vp = Vt + (size_t)hb * 64 * 1024;  // [d][s]
  int q0w = qt * 256 + w4 * 16;  // qfrag qi adds qi*128
  half8 qf[2][2];
#pragma unroll
  for (int qi = 0; qi < 2; qi++)
#pragma unroll
    for (int ks = 0; ks < 2; ks++)
#pragma unroll
      for (int j = 0; j < 8; j++)
        qf[qi][ks][j] = Qp[(size_t)(ks * 32 + qd * 8 + j) * 1024 + q0w + qi * 128 + la];
  unsigned long long mq[2][4];
#pragma unroll
  for (int qi = 0; qi < 2; qi++) {
    const ulonglong2* mp =
        (const ulonglong2*)(mbits + ((size_t)b * 1024 + q0w + qi * 128 + la) * 16 + qd * 4);
    ulonglong2 m01 = mp[0];
    ulonglong2 m23 = mp[1];
    mq[qi][0] = m01.x; mq[qi][1] = m01.y; mq[qi][2] = m23.x; mq[qi][3] = m23.y;
  }
  f32x4 acco[2][4] = {};
  float rs[2] = {0.f, 0.f};
  // K staging: physical chunk (tid&3) at row t holds logical chunk (tid&3)^f(t),
  // f(t) = (t&3)^((t>>2)&3); t = (w4&3)*16 + (lane>>2) -> f = ((tid>>2)&3)^((tid>>4)&3)
  int kt_t = (tid & 255) >> 2;
  int kt_d = (tid >> 8) * 32 + (((tid & 3) ^ ((tid >> 2) & 3) ^ ((tid >> 4) & 3)) << 3);
  // read-side physical chunk for logical chunk qd at row tsub*16+la:
  int kc8 = ((qd ^ (la & 3) ^ (la >> 2)) << 3);
  int vd = tid >> 3;
  int vt = (tid & 7) * 8;
  int vs_off = (vt >= 32 ? 2560 : 0) + vd * 40 + (vt & 31);
#if defined(HAVE_FDOT2) && defined(HAVE_PKRTZ)
  fp16x2 one2 = { (__fp16)1.0f, (__fp16)1.0f };
#endif
  {
    stage16(Kp + (size_t)kt_t * 64 + kt_d, Ks[0] + w4 * 512, lane);
    half8 vv = *(const half8*)(Vp + (size_t)vd * 1024 + vt);
    *(half8*)(Vs[0] + vs_off) = vv;
  }
  __syncthreads();
  for (int tt = 0; tt < 16; tt++) {
    int cur = tt & 1, nxt = cur ^ 1;
    half8 vvn;
    if (tt < 15) {
      vvn = *(const half8*)(Vp + (size_t)vd * 1024 + (tt + 1) * 64 + vt);
      stage16(Kp + (size_t)((tt + 1) * 64 + kt_t) * 64 + kt_d, Ks[nxt] + w4 * 512, lane);
    }
    const _Float16* ks_ = Ks[cur];
    const _Float16* vs_ = Vs[cur];
    unsigned long long mw0 = __shfl(mq[0][tt & 3], ((tt >> 2) << 4) + la);
    unsigned long long mw1 = __shfl(mq[1][tt & 3], ((tt >> 2) << 4) + la);
#pragma unroll
    for (int tsub = 0; tsub < 4; tsub++) {
      half8 kf0 = *(const half8*)(ks_ + (tsub * 16 + la) * 32 + kc8);
      half8 kf1 = *(const half8*)(ks_ + 2048 + (tsub * 16 + la) * 32 + kc8);
      f32x4 a0 = {}, a1 = {};
      a0 = __builtin_amdgcn_mfma_f32_16x16x32_f16(kf0, qf[0][0], a0, 0, 0, 0);
      a1 = __builtin_amdgcn_mfma_f32_16x16x32_f16(kf0, qf[1][0], a1, 0, 0, 0);
      a0 = __builtin_amdgcn_mfma_f32_16x16x32_f16(kf1, qf[0][1], a0, 0, 0, 0);
      a1 = __builtin_amdgcn_mfma_f32_16x16x32_f16(kf1, qf[1][1], a1, 0, 0, 0);
      half4 pf[2];
#pragma unroll
      for (int qi = 0; qi < 2; qi++) {
        const f32x4& aa = qi ? a1 : a0;
        unsigned long long mw = qi ? mw1 : mw0;
        float e0 = ((mw >> (tsub * 16 + qd * 4 + 0)) & 1ull) ? EXP2(aa[0]) : 0.0f;
        float e1 = ((mw >> (tsub * 16 + qd * 4 + 1)) & 1ull) ? EXP2(aa[1]) : 0.0f;
        float e2 = ((mw >> (tsub * 16 + qd * 4 + 2)) & 1ull) ? EXP2(aa[2]) : 0.0f;
        float e3 = ((mw >> (tsub * 16 + qd * 4 + 3)) & 1ull) ? EXP2(aa[3]) : 0.0f;
#ifdef HAVE_PKRTZ
        fp16x2 p01 = __builtin_amdgcn_cvt_pkrtz(e0, e1);
        fp16x2 p23 = __builtin_amdgcn_cvt_pkrtz(e2, e3);
        fp16x4 pfv = __builtin_shufflevector(p01, p23, 0, 1, 2, 3);
        pf[qi] = __builtin_bit_cast(half4, pfv);
#else
        pf[qi][0] = (_Float16)e0; pf[qi][1] = (_Float16)e1;
        pf[qi][2] = (_Float16)e2; pf[qi][3] = (_Float16)e3;
#endif
#if defined(HAVE_FDOT2) && defined(HAVE_PKRTZ)
        rs[qi] = __builtin_amdgcn_fdot2(p01, one2, rs[qi], false);
        rs[qi] = __builtin_amdgcn_fdot2(p23, one2, rs[qi], false);
#else
        rs[qi] += e0 + e1 + e2 + e3;
#endif
      }
#pragma unroll
      for (int nsub = 0; nsub < 4; nsub++) {
        half4 vf = *(const half4*)(vs_ + (tsub >> 1) * 2560 + (nsub * 16 + la) * 40 +
                                   (tsub & 1) * 16 + qd * 4);
        acco[0][nsub] = __builtin_amdgcn_mfma_f32_16x16x16f16(pf[0], vf, acco[0][nsub], 0, 0, 0);
        acco[1][nsub] = __builtin_amdgcn_mfma_f32_16x16x16f16(pf[1], vf, acco[1][nsub], 0, 0, 0);
      }
    }
    if (tt < 15) *(half8*)(Vs[nxt] + vs_off) = vvn;
    __syncthreads();
  }
  float* op = out + (size_t)b * 1024 * 1024 + (size_t)h * 64;
#pragma unroll
  for (int qi = 0; qi < 2; qi++) {
    float r0 = rs[qi];
    r0 += __shfl_xor(r0, 16);
    r0 += __shfl_xor(r0, 32);
    float inv_q = 1.0f / (r0 + 1e-8f);
#pragma unroll
    for (int rg = 0; rg < 4; rg++) {
      float inv = __shfl(inv_q, qd * 4 + rg);
      int s = q0w + qi * 128 + qd * 4 + rg;
#pragma unroll
      for (int nsub = 0; nsub < 4; nsub++)
        op[(size_t)s * 1024 + nsub * 16 + la] = acco[qi][nsub][rg] * inv;
    }
  }
}

extern "C" void kernel_launch(void* const* d_in, const int* in_sizes, int n_in,
                              void* d_out, int out_size, void* d_ws, size_t ws_size,
                              hipStream_t stream) {
  (void)in_sizes; (void)n_in; (void)out_size; (void)ws_size;
  const float* x = (const float*)d_in[0];
  const float* am = (const float*)d_in[1];
  const float* Wq = (const float*)d_in[2];
  const float* Wk = (const float*)d_in[3];
  const float* Wv = (const float*)d_in[4];
  float* out = (float*)d_out;

  char* p = (char*)d_ws;
  _Float16* xb = (_Float16*)p;    p += (size_t)8192 * 1024 * 2;
  _Float16* Wqkvt = (_Float16*)p; p += (size_t)3 * 1024 * 1024 * 2;
  _Float16* Qt = (_Float16*)p;    p += (size_t)8192 * 1024 * 2;   // [b,h,d,s]
  _Float16* Kh = (_Float16*)p;    p += (size_t)8192 * 1024 * 2;   // [b,h,s,d]
  _Float16* Vth = (_Float16*)p;   p += (size_t)8192 * 1024 * 2;   // [b,h,d,s]
  unsigned long long* mb = (unsigned long long*)p;

  prep_kernel<<<44032, 256, 0, stream>>>(x, am, Wq, Wk, Wv, xb, Wqkvt, mb);
  gemm_kernel<<<dim3(512), 512, 0, stream>>>(xb, Wqkvt, Qt, Kh, Vth);
  attn_kernel<<<512, 512, 0, stream>>>(Qt, Kh, Vth, mb, out);
}

// Round 4
// 247.561 us; speedup vs baseline: 1.0540x; 1.0092x over previous
//
#include <hip/hip_runtime.h>

#define KDIM 1024

typedef _Float16 half8 __attribute__((ext_vector_type(8)));
typedef _Float16 half4 __attribute__((ext_vector_type(4)));
typedef __fp16 fp16x2 __attribute__((ext_vector_type(2)));
typedef __fp16 fp16x4 __attribute__((ext_vector_type(4)));
typedef float f32x4 __attribute__((ext_vector_type(4)));

#if defined(__has_builtin)
#if __has_builtin(__builtin_amdgcn_global_load_lds)
#define HAVE_GLDS 1
#endif
#if __has_builtin(__builtin_amdgcn_exp2f)
#define EXP2(x) __builtin_amdgcn_exp2f(x)
#endif
#if __has_builtin(__builtin_amdgcn_cvt_pkrtz)
#define HAVE_PKRTZ 1
#endif
#if __has_builtin(__builtin_amdgcn_fdot2)
#define HAVE_FDOT2 1
#endif
#endif
#ifndef EXP2
#define EXP2(x) exp2f(x)
#endif

__device__ __forceinline__ void stage16(const _Float16* g, _Float16* wave_base, int lane) {
#ifdef HAVE_GLDS
  __builtin_amdgcn_global_load_lds(
      (const __attribute__((address_space(1))) void*)g,
      (__attribute__((address_space(3))) void*)wave_base, 16, 0, 0);
#else
  *(half8*)(wave_base + lane * 8) = *(const half8*)g;
#endif
}

#define BARRIER() __builtin_amdgcn_s_barrier()
#define LGKM0()                                         \
  do {                                                  \
    asm volatile("s_waitcnt lgkmcnt(0)" ::: "memory");  \
    __builtin_amdgcn_sched_barrier(0);                  \
  } while (0)
#define VMCNT(n)                                               \
  do {                                                         \
    asm volatile("s_waitcnt vmcnt(" #n ")" ::: "memory");      \
  } while (0)

// ------------- merged prep: cast x | transpose-cast W | mask bits -------------
__global__ void prep_kernel(const float* __restrict__ x, const float* __restrict__ am,
                            const float* __restrict__ Wq, const float* __restrict__ Wk,
                            const float* __restrict__ Wv, _Float16* __restrict__ xb,
                            _Float16* __restrict__ Wqkvt, unsigned long long* __restrict__ bits) {
  __shared__ _Float16 tile[32][33];
  int bid = blockIdx.x;
  if (bid < 8192) {
    size_t i = ((size_t)bid * 256 + threadIdx.x) * 4;
    float4 v = *(const float4*)(x + i);
    half4 h = { (_Float16)v.x, (_Float16)v.y, (_Float16)v.z, (_Float16)v.w };
    *(half4*)(xb + i) = h;
  } else if (bid < 11264) {
    int zz = bid - 8192;
    int z = zz >> 10;
    int rem = zz & 1023;
    int bx = rem & 31, by = rem >> 5;
    const float* src = z == 0 ? Wq : (z == 1 ? Wk : Wv);
    _Float16* dst = Wqkvt + (size_t)z * KDIM * KDIM;
    float sc = (z == 0) ? 0.18033688011112042f : 1.0f;  // (1/8)*log2(e)
    int tx = threadIdx.x & 31, ty = threadIdx.x >> 5;
    int c0 = bx * 32, r0 = by * 32;
#pragma unroll
    for (int i = 0; i < 4; i++) {
      int r = r0 + ty + i * 8;
      tile[tx][ty + i * 8] = (_Float16)(src[(size_t)r * KDIM + c0 + tx] * sc);
    }
    __syncthreads();
#pragma unroll
    for (int i = 0; i < 4; i++) {
      int n = c0 + ty + i * 8;
      dst[(size_t)n * KDIM + r0 + tx] = tile[ty + i * 8][tx];
    }
  } else {
    size_t i = (size_t)(bid - 11264) * 256 + threadIdx.x;
    unsigned long long b = __ballot(am[i] != 0.0f);
    if ((threadIdx.x & 63) == 0) bits[i >> 6] = b;
  }
}

// ---------------- fused QKV GEMM, 256x192 tile, BK=64, 3-phase counted-vmcnt ----------------
// (unchanged from previous round)
__global__ __launch_bounds__(512, 2)
void gemm_kernel(const _Float16* __restrict__ A, const _Float16* __restrict__ Bt,
                 _Float16* __restrict__ Qt, _Float16* __restrict__ Kh,
                 _Float16* __restrict__ Vth) {
  __shared__ _Float16 As[2 * 16384];   // [buf][256 rows][64]
  __shared__ _Float16 Bs[2 * 12288];   // [buf][192 rows][64]
  int tid = threadIdx.x;
  int lane = tid & 63, w = tid >> 6;
  int la = lane & 15, qd = lane >> 4;
  int wm = w & 1, wn = w >> 1;  // 2M x 4N waves; per-wave out 128 x 48 (3 n-frags strided 64)
  // XCD swizzle: 512 blocks, 64 consecutive wgs per XCD (512 % 8 == 0 -> bijective)
  int bid = blockIdx.x;
  int wg = (bid & 7) * 64 + (bid >> 3);
  int by = wg >> 4, bx = wg & 15;
  int m0 = by * 256, n0 = bx * 192;
  int srow = tid >> 3;
  int scc = ((srow & 7) ^ (tid & 7)) << 3;  // pre-swizzled source chunk (halves)
  const int rc0 = ((qd ^ (la & 7)) << 3);
  const int rc1 = (((4 | qd) ^ (la & 7)) << 3);

  const _Float16* Ab = A + (size_t)m0 * KDIM;
  const _Float16* Bb = Bt + (size_t)n0 * KDIM;

  // per-lane global staging pointers (bumped +64 halves per tile)
  const _Float16* pA0a = Ab + (size_t)(srow) * KDIM + scc;
  const _Float16* pA0b = Ab + (size_t)(srow + 64) * KDIM + scc;
  const _Float16* pA1a = Ab + (size_t)(srow + 128) * KDIM + scc;
  const _Float16* pA1b = Ab + (size_t)(srow + 192) * KDIM + scc;
  const _Float16* pB0 = Bb + (size_t)(srow) * KDIM + scc;
  const _Float16* pB1 = Bb + (size_t)(srow + 64) * KDIM + scc;
  const _Float16* pB2 = Bb + (size_t)(srow + 128) * KDIM + scc;

  _Float16* ldsAw = As + w * 512;
  _Float16* ldsBw = Bs + w * 512;

  const _Float16* baseA0 = As + wm * 4096 + la * 64 + rc0;
  const _Float16* baseA1 = As + wm * 4096 + la * 64 + rc1;
  const _Float16* baseB0 = Bs + (wn * 16 + la) * 64 + rc0;
  const _Float16* baseB1 = Bs + (wn * 16 + la) * 64 + rc1;

  f32x4 acc[8][3] = {};
  half8 af[4][2], bf0[2], bf1[2], bf2[2];

#define STAGE_A0(B)                                       \
  do {                                                    \
    stage16(pA0a, ldsAw + (B) * 16384, lane);             \
    stage16(pA0b, ldsAw + (B) * 16384 + 4096, lane);      \
    pA0a += 64; pA0b += 64;                               \
  } while (0)
#define STAGE_A1(B)                                       \
  do {                                                    \
    stage16(pA1a, ldsAw + (B) * 16384 + 8192, lane);      \
    stage16(pA1b, ldsAw + (B) * 16384 + 12288, lane);     \
    pA1a += 64; pA1b += 64;                               \
  } while (0)
#define STAGE_B0(B)                                       \
  do { stage16(pB0, ldsBw + (B) * 12288, lane); pB0 += 64; } while (0)
#define STAGE_B1(B)                                       \
  do { stage16(pB1, ldsBw + (B) * 12288 + 4096, lane); pB1 += 64; } while (0)
#define STAGE_B2(B)                                       \
  do { stage16(pB2, ldsBw + (B) * 12288 + 8192, lane); pB2 += 64; } while (0)
#define LD_AF(CUR, MH)                                                               \
  do {                                                                               \
    _Pragma("unroll") for (int mi = 0; mi < 4; ++mi) {                               \
      af[mi][0] = *(const half8*)(baseA0 + (CUR) * 16384 + (MH) * 8192 + mi * 1024); \
      af[mi][1] = *(const half8*)(baseA1 + (CUR) * 16384 + (MH) * 8192 + mi * 1024); \
    }                                                                                \
  } while (0)
#define LD_B(BF, CUR, NJ)                                                  \
  do {                                                                     \
    BF[0] = *(const half8*)(baseB0 + (CUR) * 12288 + (NJ) * 4096);         \
    BF[1] = *(const half8*)(baseB1 + (CUR) * 12288 + (NJ) * 4096);         \
  } while (0)
#define MFMA_N(MH, NJ, BF)                                                          \
  do {                                                                              \
    _Pragma("unroll") for (int mi = 0; mi < 4; ++mi) {                              \
      acc[(MH) * 4 + mi][NJ] = __builtin_amdgcn_mfma_f32_16x16x32_f16(              \
          af[mi][0], BF[0], acc[(MH) * 4 + mi][NJ], 0, 0, 0);                       \
      acc[(MH) * 4 + mi][NJ] = __builtin_amdgcn_mfma_f32_16x16x32_f16(              \
          af[mi][1], BF[1], acc[(MH) * 4 + mi][NJ], 0, 0, 0);                       \
    }                                                                               \
  } while (0)

  // Prologue: tile0 fully (7 loads), drain, barrier.
  STAGE_A0(0); STAGE_B0(0); STAGE_A1(0); STAGE_B1(0); STAGE_B2(0);
  VMCNT(0);
  BARRIER();

#define KTILE(T, CUR, NXT)                                     \
  do {                                                         \
    int t = (T);                                               \
    /* phase 1 */                                              \
    LD_AF(CUR, 0);                                             \
    LD_B(bf0, CUR, 0);                                         \
    if (t < 15) { STAGE_A0(NXT); STAGE_B0(NXT); }              \
    BARRIER();                                                 \
    LGKM0();                                                   \
    __builtin_amdgcn_s_setprio(1);                             \
    MFMA_N(0, 0, bf0);                                         \
    __builtin_amdgcn_s_setprio(0);                             \
    if (t < 15) { VMCNT(3); } else { VMCNT(0); }               \
    BARRIER();                                                 \
    /* phase 2 */                                              \
    LD_B(bf1, CUR, 1);                                         \
    LD_B(bf2, CUR, 2);                                         \
    if (t < 15) STAGE_A1(NXT);                                 \
    BARRIER();                                                 \
    LGKM0();                                                   \
    __builtin_amdgcn_s_setprio(1);                             \
    MFMA_N(0, 1, bf1);                                         \
    MFMA_N(0, 2, bf2);                                         \
    __builtin_amdgcn_s_setprio(0);                             \
    BARRIER();                                                 \
    /* phase 3 */                                              \
    LD_AF(CUR, 1);                                             \
    if (t < 15) { STAGE_B1(NXT); STAGE_B2(NXT); }              \
    BARRIER();                                                 \
    LGKM0();                                                   \
    __builtin_amdgcn_s_setprio(1);                             \
    MFMA_N(1, 0, bf0);                                         \
    MFMA_N(1, 1, bf1);                                         \
    MFMA_N(1, 2, bf2);                                         \
    __builtin_amdgcn_s_setprio(0);                             \
    if (t < 15) { VMCNT(4); }                                  \
    BARRIER();                                                 \
  } while (0)

#pragma unroll 1
  for (int tp = 0; tp < 8; ++tp) {
    KTILE(2 * tp, 0, 1);
    KTILE(2 * tp + 1, 1, 0);
  }

#undef KTILE
#undef MFMA_N
#undef LD_B
#undef LD_AF
#undef STAGE_B2
#undef STAGE_B1
#undef STAGE_B0
#undef STAGE_A1
#undef STAGE_A0

  // ---------------- epilogue (per-frag Q/K/V routing: 192-col tiles span matrices) ----------
  int rr = lane >> 2, c4 = lane & 3;
  _Float16* ep = As + w * 1280;  // wave-private 16x72 transpose patch
#pragma unroll
  for (int mh = 0; mh < 2; ++mh) {
    int srow0 = m0 + mh * 128 + wm * 64;
    int b = srow0 >> 10, s0 = srow0 & 1023;
#pragma unroll
    for (int nj = 0; nj < 3; ++nj) {
      int colh = n0 + wn * 16 + nj * 64;
      int whichf = colh >> 10;       // 0:Q 1:K 2:V (uniform per wave,nj)
      int cm = colh & 1023;
      int hh = cm >> 6, d0 = cm & 63;
      if (whichf == 1) {
        _Float16* kb = Kh + (size_t)(b * 16 + hh) * 1024 * 64;
#pragma unroll
        for (int mi = 0; mi < 4; ++mi) {
          f32x4 v = acc[mh * 4 + mi][nj];
          int s = s0 + mi * 16 + qd * 4;
#pragma unroll
          for (int rg = 0; rg < 4; ++rg)
            kb[(size_t)(s + rg) * 64 + d0 + la] = (_Float16)v[rg];
        }
      } else {
        _Float16* dst = (whichf == 0) ? Qt : Vth;
#pragma unroll
        for (int mi = 0; mi < 4; ++mi) {
          f32x4 v = acc[mh * 4 + mi][nj];
          half4 hv = { (_Float16)v[0], (_Float16)v[1], (_Float16)v[2], (_Float16)v[3] };
          *(half4*)(ep + la * 72 + mi * 16 + qd * 4) = hv;  // row=d(la), col=s
        }
        half8 o0 = *(const half8*)(ep + rr * 72 + c4 * 16);
        half8 o1 = *(const half8*)(ep + rr * 72 + c4 * 16 + 8);
        _Float16* gp = dst + ((size_t)(b * 16 + hh) * 64 + d0 + rr) * 1024 + s0 + c4 * 16;
        *(half8*)gp = o0;
        *(half8*)(gp + 8) = o1;
      }
    }
  }
}

// ---------------- fused attention: 4-buf K, 2-ahead staging, counted vmcnt, setprio ----------
__global__ __launch_bounds__(512, 2)
void attn_kernel(const _Float16* __restrict__ Qt, const _Float16* __restrict__ K,
                 const _Float16* __restrict__ Vt, const unsigned long long* __restrict__ mbits,
                 float* __restrict__ out) {
  __shared__ _Float16 Ks[4][2 * 64 * 32];  // 4 buffers, 2-ahead pipeline (8KB each)
  __shared__ _Float16 Vs[2][2 * 64 * 40];  // [buf][tc=t/32][d][40 padded]
  int tid = threadIdx.x;
  int lane = tid & 63, w4 = tid >> 6;  // w4 0..7
  int la = lane & 15, qd = lane >> 4;
  int linear = blockIdx.x;
  int xlo = linear & 7;
  int tmp = linear >> 3;  // 0..63
  int qt = tmp & 3;
  int hb = (tmp >> 2) * 8 + xlo;  // 0..127
  int h = hb & 15, b = hb >> 4;
  const _Float16* Qp = Qt + (size_t)hb * 64 * 1024;  // [d][s]
  const _Float16* Kp = K + (size_t)hb * 1024 * 64;   // [s][d]
  const _Float16* Vp = Vt + (size_t)hb * 64 * 1024;  // [d][s]
  int q0w = qt * 256 + w4 * 16;  // qfrag qi adds qi*128
  half8 qf[2][2];
#pragma unroll
  for (int qi = 0; qi < 2; qi++)
#pragma unroll
    for (int ks = 0; ks < 2; ks++)
#pragma unroll
      for (int j = 0; j < 8; j++)
        qf[qi][ks][j] = Qp[(size_t)(ks * 32 + qd * 8 + j) * 1024 + q0w + qi * 128 + la];
  unsigned long long mq[2][4];
#pragma unroll
  for (int qi = 0; qi < 2; qi++) {
    const ulonglong2* mp =
        (const ulonglong2*)(mbits + ((size_t)b * 1024 + q0w + qi * 128 + la) * 16 + qd * 4);
    ulonglong2 m01 = mp[0];
    ulonglong2 m23 = mp[1];
    mq[qi][0] = m01.x; mq[qi][1] = m01.y; mq[qi][2] = m23.x; mq[qi][3] = m23.y;
  }
  f32x4 acco[2][4] = {};
  float rs[2] = {0.f, 0.f};
  // K staging geometry (chunk-XOR kept from prior round; neutral but validated)
  int kt_t = (tid & 255) >> 2;
  int kt_d = (tid >> 8) * 32 + (((tid & 3) ^ ((tid >> 2) & 3) ^ ((tid >> 4) & 3)) << 3);
  int kc8 = ((qd ^ (la & 3) ^ (la >> 2)) << 3);
  int vd = tid >> 3;
  int vt = (tid & 7) * 8;
  int vs_off = (vt >= 32 ? 2560 : 0) + vd * 40 + (vt & 31);
#if defined(HAVE_FDOT2) && defined(HAVE_PKRTZ)
  fp16x2 one2 = { (__fp16)1.0f, (__fp16)1.0f };
#endif
  // prologue: issue V(0) first (oldest), then K(0), K(1); leave K(1) in flight.
  {
    half8 vv0 = *(const half8*)(Vp + (size_t)vd * 1024 + vt);
    __builtin_amdgcn_sched_barrier(0);
    stage16(Kp + (size_t)kt_t * 64 + kt_d, Ks[0] + w4 * 512, lane);
    stage16(Kp + (size_t)(64 + kt_t) * 64 + kt_d, Ks[1] + w4 * 512, lane);
    *(half8*)(Vs[0] + vs_off) = vv0;  // implicit wait retires vv0 (and nothing newer)
  }
  asm volatile("s_waitcnt vmcnt(1) lgkmcnt(0)" ::: "memory");
  BARRIER();
  for (int tt = 0; tt < 16; tt++) {
    const _Float16* ks_ = Ks[tt & 3];
    const _Float16* vs_ = Vs[tt & 1];
    half8 vvn;
    if (tt < 15) {
      vvn = *(const half8*)(Vp + (size_t)vd * 1024 + (tt + 1) * 64 + vt);
      __builtin_amdgcn_sched_barrier(0);
    }
    if (tt < 14)
      stage16(Kp + (size_t)((tt + 2) * 64 + kt_t) * 64 + kt_d, Ks[(tt + 2) & 3] + w4 * 512, lane);
    unsigned long long mw0 = __shfl(mq[0][tt & 3], ((tt >> 2) << 4) + la);
    unsigned long long mw1 = __shfl(mq[1][tt & 3], ((tt >> 2) << 4) + la);
    unsigned long long mq0s = mw0 >> (qd * 4);
    unsigned long long mq1s = mw1 >> (qd * 4);
#pragma unroll
    for (int tsub = 0; tsub < 4; tsub++) {
      half8 kf0 = *(const half8*)(ks_ + (tsub * 16 + la) * 32 + kc8);
      half8 kf1 = *(const half8*)(ks_ + 2048 + (tsub * 16 + la) * 32 + kc8);
      f32x4 a0 = {}, a1 = {};
      __builtin_amdgcn_s_setprio(1);
      a0 = __builtin_amdgcn_mfma_f32_16x16x32_f16(kf0, qf[0][0], a0, 0, 0, 0);
      a1 = __builtin_amdgcn_mfma_f32_16x16x32_f16(kf0, qf[1][0], a1, 0, 0, 0);
      a0 = __builtin_amdgcn_mfma_f32_16x16x32_f16(kf1, qf[0][1], a0, 0, 0, 0);
      a1 = __builtin_amdgcn_mfma_f32_16x16x32_f16(kf1, qf[1][1], a1, 0, 0, 0);
      __builtin_amdgcn_s_setprio(0);
      half4 pf[2];
#pragma unroll
      for (int qi = 0; qi < 2; qi++) {
        const f32x4& aa = qi ? a1 : a0;
        unsigned nib = (unsigned)((qi ? mq1s : mq0s) >> (tsub * 16)) & 15u;
        float e0 = (nib & 1u) ? EXP2(aa[0]) : 0.0f;
        float e1 = (nib & 2u) ? EXP2(aa[1]) : 0.0f;
        float e2 = (nib & 4u) ? EXP2(aa[2]) : 0.0f;
        float e3 = (nib & 8u) ? EXP2(aa[3]) : 0.0f;
#ifdef HAVE_PKRTZ
        fp16x2 p01 = __builtin_amdgcn_cvt_pkrtz(e0, e1);
        fp16x2 p23 = __builtin_amdgcn_cvt_pkrtz(e2, e3);
        fp16x4 pfv = __builtin_shufflevector(p01, p23, 0, 1, 2, 3);
        pf[qi] = __builtin_bit_cast(half4, pfv);
#else
        pf[qi][0] = (_Float16)e0; pf[qi][1] = (_Float16)e1;
        pf[qi][2] = (_Float16)e2; pf[qi][3] = (_Float16)e3;
#endif
#if defined(HAVE_FDOT2) && defined(HAVE_PKRTZ)
        rs[qi] = __builtin_amdgcn_fdot2(p01, one2, rs[qi], false);
        rs[qi] = __builtin_amdgcn_fdot2(p23, one2, rs[qi], false);
#else
        rs[qi] += e0 + e1 + e2 + e3;
#endif
      }
#pragma unroll
      for (int nsub = 0; nsub < 4; nsub++) {
        half4 vf = *(const half4*)(vs_ + (tsub >> 1) * 2560 + (nsub * 16 + la) * 40 +
                                   (tsub & 1) * 16 + qd * 4);
        __builtin_amdgcn_s_setprio(1);
        acco[0][nsub] = __builtin_amdgcn_mfma_f32_16x16x16f16(pf[0], vf, acco[0][nsub], 0, 0, 0);
        acco[1][nsub] = __builtin_amdgcn_mfma_f32_16x16x16f16(pf[1], vf, acco[1][nsub], 0, 0, 0);
        __builtin_amdgcn_s_setprio(0);
      }
    }
    if (tt < 15) *(half8*)(Vs[(tt + 1) & 1] + vs_off) = vvn;
    if (tt < 14) {
      // implicit vvn-wait already retired K(tt+1); keep only K(tt+2) in flight
      asm volatile("s_waitcnt vmcnt(1) lgkmcnt(0)" ::: "memory");
      BARRIER();
    } else if (tt == 14) {
      asm volatile("s_waitcnt vmcnt(0) lgkmcnt(0)" ::: "memory");
      BARRIER();
    }
  }
  float* op = out + (size_t)b * 1024 * 1024 + (size_t)h * 64;
#pragma unroll
  for (int qi = 0; qi < 2; qi++) {
    float r0 = rs[qi];
    r0 += __shfl_xor(r0, 16);
    r0 += __shfl_xor(r0, 32);
    float inv_q = 1.0f / (r0 + 1e-8f);
#pragma unroll
    for (int rg = 0; rg < 4; rg++) {
      float inv = __shfl(inv_q, qd * 4 + rg);
      int s = q0w + qi * 128 + qd * 4 + rg;
#pragma unroll
      for (int nsub = 0; nsub < 4; nsub++)
        op[(size_t)s * 1024 + nsub * 16 + la] = acco[qi][nsub][rg] * inv;
    }
  }
}

extern "C" void kernel_launch(void* const* d_in, const int* in_sizes, int n_in,
                              void* d_out, int out_size, void* d_ws, size_t ws_size,
                              hipStream_t stream) {
  (void)in_sizes; (void)n_in; (void)out_size; (void)ws_size;
  const float* x = (const float*)d_in[0];
  const float* am = (const float*)d_in[1];
  const float* Wq = (const float*)d_in[2];
  const float* Wk = (const float*)d_in[3];
  const float* Wv = (const float*)d_in[4];
  float* out = (float*)d_out;

  char* p = (char*)d_ws;
  _Float16* xb = (_Float16*)p;    p += (size_t)8192 * 1024 * 2;
  _Float16* Wqkvt = (_Float16*)p; p += (size_t)3 * 1024 * 1024 * 2;
  _Float16* Qt = (_Float16*)p;    p += (size_t)8192 * 1024 * 2;   // [b,h,d,s]
  _Float16* Kh = (_Float16*)p;    p += (size_t)8192 * 1024 * 2;   // [b,h,s,d]
  _Float16* Vth = (_Float16*)p;   p += (size_t)8192 * 1024 * 2;   // [b,h,d,s]
  unsigned long long* mb = (unsigned long long*)p;

  prep_kernel<<<44032, 256, 0, stream>>>(x, am, Wq, Wk, Wv, xb, Wqkvt, mb);
  gemm_kernel<<<dim3(512), 512, 0, stream>>>(xb, Wqkvt, Qt, Kh, Vth);
  attn_kernel<<<512, 512, 0, stream>>>(Qt, Kh, Vth, mb, out);
}

// Round 5
// 246.282 us; speedup vs baseline: 1.0595x; 1.0052x over previous
//
#include <hip/hip_runtime.h>

#define KDIM 1024

typedef _Float16 half8 __attribute__((ext_vector_type(8)));
typedef _Float16 half4 __attribute__((ext_vector_type(4)));
typedef __fp16 fp16x2 __attribute__((ext_vector_type(2)));
typedef __fp16 fp16x4 __attribute__((ext_vector_type(4)));
typedef float f32x4 __attribute__((ext_vector_type(4)));

#if defined(__has_builtin)
#if __has_builtin(__builtin_amdgcn_global_load_lds)
#define HAVE_GLDS 1
#endif
#if __has_builtin(__builtin_amdgcn_exp2f)
#define EXP2(x) __builtin_amdgcn_exp2f(x)
#endif
#if __has_builtin(__builtin_amdgcn_cvt_pkrtz)
#define HAVE_PKRTZ 1
#endif
#if __has_builtin(__builtin_amdgcn_fdot2)
#define HAVE_FDOT2 1
#endif
#endif
#ifndef EXP2
#define EXP2(x) exp2f(x)
#endif

__device__ __forceinline__ void stage16(const _Float16* g, _Float16* wave_base, int lane) {
#ifdef HAVE_GLDS
  __builtin_amdgcn_global_load_lds(
      (const __attribute__((address_space(1))) void*)g,
      (__attribute__((address_space(3))) void*)wave_base, 16, 0, 0);
#else
  *(half8*)(wave_base + lane * 8) = *(const half8*)g;
#endif
}

#define BARRIER() __builtin_amdgcn_s_barrier()
#define LGKM0()                                         \
  do {                                                  \
    asm volatile("s_waitcnt lgkmcnt(0)" ::: "memory");  \
    __builtin_amdgcn_sched_barrier(0);                  \
  } while (0)
#define VMCNT(n)                                               \
  do {                                                         \
    asm volatile("s_waitcnt vmcnt(" #n ")" ::: "memory");      \
  } while (0)

// ------------- merged prep: cast x | transpose-cast W | mask bits -------------
__global__ void prep_kernel(const float* __restrict__ x, const float* __restrict__ am,
                            const float* __restrict__ Wq, const float* __restrict__ Wk,
                            const float* __restrict__ Wv, _Float16* __restrict__ xb,
                            _Float16* __restrict__ Wqkvt, unsigned long long* __restrict__ bits) {
  __shared__ _Float16 tile[32][33];
  int bid = blockIdx.x;
  if (bid < 8192) {
    size_t i = ((size_t)bid * 256 + threadIdx.x) * 4;
    float4 v = *(const float4*)(x + i);
    half4 h = { (_Float16)v.x, (_Float16)v.y, (_Float16)v.z, (_Float16)v.w };
    *(half4*)(xb + i) = h;
  } else if (bid < 11264) {
    int zz = bid - 8192;
    int z = zz >> 10;
    int rem = zz & 1023;
    int bx = rem & 31, by = rem >> 5;
    const float* src = z == 0 ? Wq : (z == 1 ? Wk : Wv);
    _Float16* dst = Wqkvt + (size_t)z * KDIM * KDIM;
    float sc = (z == 0) ? 0.18033688011112042f : 1.0f;  // (1/8)*log2(e)
    int tx = threadIdx.x & 31, ty = threadIdx.x >> 5;
    int c0 = bx * 32, r0 = by * 32;
#pragma unroll
    for (int i = 0; i < 4; i++) {
      int r = r0 + ty + i * 8;
      tile[tx][ty + i * 8] = (_Float16)(src[(size_t)r * KDIM + c0 + tx] * sc);
    }
    __syncthreads();
#pragma unroll
    for (int i = 0; i < 4; i++) {
      int n = c0 + ty + i * 8;
      dst[(size_t)n * KDIM + r0 + tx] = tile[ty + i * 8][tx];
    }
  } else {
    size_t i = (size_t)(bid - 11264) * 256 + threadIdx.x;
    unsigned long long b = __ballot(am[i] != 0.0f);
    if ((threadIdx.x & 63) == 0) bits[i >> 6] = b;
  }
}

// ---------------- fused QKV GEMM, 256x192 tile, BK=64, 3-phase counted-vmcnt ----------------
// (byte-identical to previous round)
__global__ __launch_bounds__(512, 2)
void gemm_kernel(const _Float16* __restrict__ A, const _Float16* __restrict__ Bt,
                 _Float16* __restrict__ Qt, _Float16* __restrict__ Kh,
                 _Float16* __restrict__ Vth) {
  __shared__ _Float16 As[2 * 16384];   // [buf][256 rows][64]
  __shared__ _Float16 Bs[2 * 12288];   // [buf][192 rows][64]
  int tid = threadIdx.x;
  int lane = tid & 63, w = tid >> 6;
  int la = lane & 15, qd = lane >> 4;
  int wm = w & 1, wn = w >> 1;  // 2M x 4N waves; per-wave out 128 x 48 (3 n-frags strided 64)
  // XCD swizzle: 512 blocks, 64 consecutive wgs per XCD (512 % 8 == 0 -> bijective)
  int bid = blockIdx.x;
  int wg = (bid & 7) * 64 + (bid >> 3);
  int by = wg >> 4, bx = wg & 15;
  int m0 = by * 256, n0 = bx * 192;
  int srow = tid >> 3;
  int scc = ((srow & 7) ^ (tid & 7)) << 3;  // pre-swizzled source chunk (halves)
  const int rc0 = ((qd ^ (la & 7)) << 3);
  const int rc1 = (((4 | qd) ^ (la & 7)) << 3);

  const _Float16* Ab = A + (size_t)m0 * KDIM;
  const _Float16* Bb = Bt + (size_t)n0 * KDIM;

  // per-lane global staging pointers (bumped +64 halves per tile)
  const _Float16* pA0a = Ab + (size_t)(srow) * KDIM + scc;
  const _Float16* pA0b = Ab + (size_t)(srow + 64) * KDIM + scc;
  const _Float16* pA1a = Ab + (size_t)(srow + 128) * KDIM + scc;
  const _Float16* pA1b = Ab + (size_t)(srow + 192) * KDIM + scc;
  const _Float16* pB0 = Bb + (size_t)(srow) * KDIM + scc;
  const _Float16* pB1 = Bb + (size_t)(srow + 64) * KDIM + scc;
  const _Float16* pB2 = Bb + (size_t)(srow + 128) * KDIM + scc;

  _Float16* ldsAw = As + w * 512;
  _Float16* ldsBw = Bs + w * 512;

  const _Float16* baseA0 = As + wm * 4096 + la * 64 + rc0;
  const _Float16* baseA1 = As + wm * 4096 + la * 64 + rc1;
  const _Float16* baseB0 = Bs + (wn * 16 + la) * 64 + rc0;
  const _Float16* baseB1 = Bs + (wn * 16 + la) * 64 + rc1;

  f32x4 acc[8][3] = {};
  half8 af[4][2], bf0[2], bf1[2], bf2[2];

#define STAGE_A0(B)                                       \
  do {                                                    \
    stage16(pA0a, ldsAw + (B) * 16384, lane);             \
    stage16(pA0b, ldsAw + (B) * 16384 + 4096, lane);      \
    pA0a += 64; pA0b += 64;                               \
  } while (0)
#define STAGE_A1(B)                                       \
  do {                                                    \
    stage16(pA1a, ldsAw + (B) * 16384 + 8192, lane);      \
    stage16(pA1b, ldsAw + (B) * 16384 + 12288, lane);     \
    pA1a += 64; pA1b += 64;                               \
  } while (0)
#define STAGE_B0(B)                                       \
  do { stage16(pB0, ldsBw + (B) * 12288, lane); pB0 += 64; } while (0)
#define STAGE_B1(B)                                       \
  do { stage16(pB1, ldsBw + (B) * 12288 + 4096, lane); pB1 += 64; } while (0)
#define STAGE_B2(B)                                       \
  do { stage16(pB2, ldsBw + (B) * 12288 + 8192, lane); pB2 += 64; } while (0)
#define LD_AF(CUR, MH)                                                               \
  do {                                                                               \
    _Pragma("unroll") for (int mi = 0; mi < 4; ++mi) {                               \
      af[mi][0] = *(const half8*)(baseA0 + (CUR) * 16384 + (MH) * 8192 + mi * 1024); \
      af[mi][1] = *(const half8*)(baseA1 + (CUR) * 16384 + (MH) * 8192 + mi * 1024); \
    }                                                                                \
  } while (0)
#define LD_B(BF, CUR, NJ)                                                  \
  do {                                                                     \
    BF[0] = *(const half8*)(baseB0 + (CUR) * 12288 + (NJ) * 4096);         \
    BF[1] = *(const half8*)(baseB1 + (CUR) * 12288 + (NJ) * 4096);         \
  } while (0)
#define MFMA_N(MH, NJ, BF)                                                          \
  do {                                                                              \
    _Pragma("unroll") for (int mi = 0; mi < 4; ++mi) {                              \
      acc[(MH) * 4 + mi][NJ] = __builtin_amdgcn_mfma_f32_16x16x32_f16(              \
          af[mi][0], BF[0], acc[(MH) * 4 + mi][NJ], 0, 0, 0);                       \
      acc[(MH) * 4 + mi][NJ] = __builtin_amdgcn_mfma_f32_16x16x32_f16(              \
          af[mi][1], BF[1], acc[(MH) * 4 + mi][NJ], 0, 0, 0);                       \
    }                                                                               \
  } while (0)

  // Prologue: tile0 fully (7 loads), drain, barrier.
  STAGE_A0(0); STAGE_B0(0); STAGE_A1(0); STAGE_B1(0); STAGE_B2(0);
  VMCNT(0);
  BARRIER();

#define KTILE(T, CUR, NXT)                                     \
  do {                                                         \
    int t = (T);                                               \
    /* phase 1 */                                              \
    LD_AF(CUR, 0);                                             \
    LD_B(bf0, CUR, 0);                                         \
    if (t < 15) { STAGE_A0(NXT); STAGE_B0(NXT); }              \
    BARRIER();                                                 \
    LGKM0();                                                   \
    __builtin_amdgcn_s_setprio(1);                             \
    MFMA_N(0, 0, bf0);                                         \
    __builtin_amdgcn_s_setprio(0);                             \
    if (t < 15) { VMCNT(3); } else { VMCNT(0); }               \
    BARRIER();                                                 \
    /* phase 2 */                                              \
    LD_B(bf1, CUR, 1);                                         \
    LD_B(bf2, CUR, 2);                                         \
    if (t < 15) STAGE_A1(NXT);                                 \
    BARRIER();                                                 \
    LGKM0();                                                   \
    __builtin_amdgcn_s_setprio(1);                             \
    MFMA_N(0, 1, bf1);                                         \
    MFMA_N(0, 2, bf2);                                         \
    __builtin_amdgcn_s_setprio(0);                             \
    BARRIER();                                                 \
    /* phase 3 */                                              \
    LD_AF(CUR, 1);                                             \
    if (t < 15) { STAGE_B1(NXT); STAGE_B2(NXT); }              \
    BARRIER();                                                 \
    LGKM0();                                                   \
    __builtin_amdgcn_s_setprio(1);                             \
    MFMA_N(1, 0, bf0);                                         \
    MFMA_N(1, 1, bf1);                                         \
    MFMA_N(1, 2, bf2);                                         \
    __builtin_amdgcn_s_setprio(0);                             \
    if (t < 15) { VMCNT(4); }                                  \
    BARRIER();                                                 \
  } while (0)

#pragma unroll 1
  for (int tp = 0; tp < 8; ++tp) {
    KTILE(2 * tp, 0, 1);
    KTILE(2 * tp + 1, 1, 0);
  }

#undef KTILE
#undef MFMA_N
#undef LD_B
#undef LD_AF
#undef STAGE_B2
#undef STAGE_B1
#undef STAGE_B0
#undef STAGE_A1
#undef STAGE_A0

  // ---------------- epilogue (per-frag Q/K/V routing: 192-col tiles span matrices) ----------
  int rr = lane >> 2, c4 = lane & 3;
  _Float16* ep = As + w * 1280;  // wave-private 16x72 transpose patch
#pragma unroll
  for (int mh = 0; mh < 2; ++mh) {
    int srow0 = m0 + mh * 128 + wm * 64;
    int b = srow0 >> 10, s0 = srow0 & 1023;
#pragma unroll
    for (int nj = 0; nj < 3; ++nj) {
      int colh = n0 + wn * 16 + nj * 64;
      int whichf = colh >> 10;       // 0:Q 1:K 2:V (uniform per wave,nj)
      int cm = colh & 1023;
      int hh = cm >> 6, d0 = cm & 63;
      if (whichf == 1) {
        _Float16* kb = Kh + (size_t)(b * 16 + hh) * 1024 * 64;
#pragma unroll
        for (int mi = 0; mi < 4; ++mi) {
          f32x4 v = acc[mh * 4 + mi][nj];
          int s = s0 + mi * 16 + qd * 4;
#pragma unroll
          for (int rg = 0; rg < 4; ++rg)
            kb[(size_t)(s + rg) * 64 + d0 + la] = (_Float16)v[rg];
        }
      } else {
        _Float16* dst = (whichf == 0) ? Qt : Vth;
#pragma unroll
        for (int mi = 0; mi < 4; ++mi) {
          f32x4 v = acc[mh * 4 + mi][nj];
          half4 hv = { (_Float16)v[0], (_Float16)v[1], (_Float16)v[2], (_Float16)v[3] };
          *(half4*)(ep + la * 72 + mi * 16 + qd * 4) = hv;  // row=d(la), col=s
        }
        half8 o0 = *(const half8*)(ep + rr * 72 + c4 * 16);
        half8 o1 = *(const half8*)(ep + rr * 72 + c4 * 16 + 8);
        _Float16* gp = dst + ((size_t)(b * 16 + hh) * 64 + d0 + rr) * 1024 + s0 + c4 * 16;
        *(half8*)gp = o0;
        *(half8*)(gp + 8) = o1;
      }
    }
  }
}

// ---------------- fused attention: qt=8 split (1024 blocks, 3/CU), 4-buf K pipeline ----------
__global__ __launch_bounds__(512, 2)
void attn_kernel(const _Float16* __restrict__ Qt, const _Float16* __restrict__ K,
                 const _Float16* __restrict__ Vt, const unsigned long long* __restrict__ mbits,
                 float* __restrict__ out) {
  __shared__ _Float16 Ks[4][2 * 64 * 32];  // 4 buffers, 2-ahead pipeline (8KB each)
  __shared__ _Float16 Vs[2][2 * 64 * 40];  // [buf][tc=t/32][d][40 padded]
  int tid = threadIdx.x;
  int lane = tid & 63, w4 = tid >> 6;  // w4 0..7
  int la = lane & 15, qd = lane >> 4;
  // 1024 blocks: all 8 qt-siblings of a head share an XCD (share K/V in its L2)
  int linear = blockIdx.x;
  int xlo = linear & 7;
  int tmp = linear >> 3;          // 0..127
  int qt = tmp & 7;               // 0..7
  int hb = (tmp >> 3) * 8 + xlo;  // 0..127
  int h = hb & 15, b = hb >> 4;
  const _Float16* Qp = Qt + (size_t)hb * 64 * 1024;  // [d][s]
  const _Float16* Kp = K + (size_t)hb * 1024 * 64;   // [s][d]
  const _Float16* Vp = Vt + (size_t)hb * 64 * 1024;  // [d][s]
  int q0w = qt * 128 + w4 * 16;  // 16 q-rows per wave
  half8 qf[2];
#pragma unroll
  for (int ks = 0; ks < 2; ks++)
#pragma unroll
    for (int j = 0; j < 8; j++)
      qf[ks][j] = Qp[(size_t)(ks * 32 + qd * 8 + j) * 1024 + q0w + la];
  unsigned long long mq[4];
  {
    const ulonglong2* mp =
        (const ulonglong2*)(mbits + ((size_t)b * 1024 + q0w + la) * 16 + qd * 4);
    ulonglong2 m01 = mp[0];
    ulonglong2 m23 = mp[1];
    mq[0] = m01.x; mq[1] = m01.y; mq[2] = m23.x; mq[3] = m23.y;
  }
  f32x4 acco[4] = {};
  float rs = 0.f;
  // K staging geometry (chunk-XOR involution kept; validated)
  int kt_t = (tid & 255) >> 2;
  int kt_d = (tid >> 8) * 32 + (((tid & 3) ^ ((tid >> 2) & 3) ^ ((tid >> 4) & 3)) << 3);
  int kc8 = ((qd ^ (la & 3) ^ (la >> 2)) << 3);
  int vd = tid >> 3;
  int vt = (tid & 7) * 8;
  int vs_off = (vt >= 32 ? 2560 : 0) + vd * 40 + (vt & 31);
#if defined(HAVE_FDOT2) && defined(HAVE_PKRTZ)
  fp16x2 one2 = { (__fp16)1.0f, (__fp16)1.0f };
#endif
  // prologue: issue V(0) first (oldest), then K(0), K(1); leave K(1) in flight.
  {
    half8 vv0 = *(const half8*)(Vp + (size_t)vd * 1024 + vt);
    __builtin_amdgcn_sched_barrier(0);
    stage16(Kp + (size_t)kt_t * 64 + kt_d, Ks[0] + w4 * 512, lane);
    stage16(Kp + (size_t)(64 + kt_t) * 64 + kt_d, Ks[1] + w4 * 512, lane);
    *(half8*)(Vs[0] + vs_off) = vv0;  // implicit wait retires vv0 (and nothing newer)
  }
  asm volatile("s_waitcnt vmcnt(1) lgkmcnt(0)" ::: "memory");
  BARRIER();
  for (int tt = 0; tt < 16; tt++) {
    const _Float16* ks_ = Ks[tt & 3];
    const _Float16* vs_ = Vs[tt & 1];
    half8 vvn;
    if (tt < 15) {
      vvn = *(const half8*)(Vp + (size_t)vd * 1024 + (tt + 1) * 64 + vt);
      __builtin_amdgcn_sched_barrier(0);
    }
    if (tt < 14)
      stage16(Kp + (size_t)((tt + 2) * 64 + kt_t) * 64 + kt_d, Ks[(tt + 2) & 3] + w4 * 512, lane);
    unsigned long long mw = __shfl(mq[tt & 3], ((tt >> 2) << 4) + la);
    unsigned long long mqs = mw >> (qd * 4);
#pragma unroll
    for (int tsub = 0; tsub < 4; tsub++) {
      half8 kf0 = *(const half8*)(ks_ + (tsub * 16 + la) * 32 + kc8);
      half8 kf1 = *(const half8*)(ks_ + 2048 + (tsub * 16 + la) * 32 + kc8);
      f32x4 a0 = {};
      __builtin_amdgcn_s_setprio(1);
      a0 = __builtin_amdgcn_mfma_f32_16x16x32_f16(kf0, qf[0], a0, 0, 0, 0);
      a0 = __builtin_amdgcn_mfma_f32_16x16x32_f16(kf1, qf[1], a0, 0, 0, 0);
      __builtin_amdgcn_s_setprio(0);
      unsigned nib = (unsigned)(mqs >> (tsub * 16)) & 15u;
      float e0 = (nib & 1u) ? EXP2(a0[0]) : 0.0f;
      float e1 = (nib & 2u) ? EXP2(a0[1]) : 0.0f;
      float e2 = (nib & 4u) ? EXP2(a0[2]) : 0.0f;
      float e3 = (nib & 8u) ? EXP2(a0[3]) : 0.0f;
      half4 pf;
#ifdef HAVE_PKRTZ
      fp16x2 p01 = __builtin_amdgcn_cvt_pkrtz(e0, e1);
      fp16x2 p23 = __builtin_amdgcn_cvt_pkrtz(e2, e3);
      fp16x4 pfv = __builtin_shufflevector(p01, p23, 0, 1, 2, 3);
      pf = __builtin_bit_cast(half4, pfv);
#else
      pf[0] = (_Float16)e0; pf[1] = (_Float16)e1;
      pf[2] = (_Float16)e2; pf[3] = (_Float16)e3;
#endif
#if defined(HAVE_FDOT2) && defined(HAVE_PKRTZ)
      rs = __builtin_amdgcn_fdot2(p01, one2, rs, false);
      rs = __builtin_amdgcn_fdot2(p23, one2, rs, false);
#else
      rs += e0 + e1 + e2 + e3;
#endif
#pragma unroll
      for (int nsub = 0; nsub < 4; nsub++) {
        half4 vf = *(const half4*)(vs_ + (tsub >> 1) * 2560 + (nsub * 16 + la) * 40 +
                                   (tsub & 1) * 16 + qd * 4);
        __builtin_amdgcn_s_setprio(1);
        acco[nsub] = __builtin_amdgcn_mfma_f32_16x16x16f16(pf, vf, acco[nsub], 0, 0, 0);
        __builtin_amdgcn_s_setprio(0);
      }
    }
    if (tt < 15) *(half8*)(Vs[(tt + 1) & 1] + vs_off) = vvn;
    if (tt < 14) {
      // implicit vvn-wait already retired K(tt+1); keep only K(tt+2) in flight
      asm volatile("s_waitcnt vmcnt(1) lgkmcnt(0)" ::: "memory");
      BARRIER();
    } else if (tt == 14) {
      asm volatile("s_waitcnt vmcnt(0) lgkmcnt(0)" ::: "memory");
      BARRIER();
    }
  }
  float* op = out + (size_t)b * 1024 * 1024 + (size_t)h * 64;
  {
    float r0 = rs;
    r0 += __shfl_xor(r0, 16);
    r0 += __shfl_xor(r0, 32);
    float inv_q = 1.0f / (r0 + 1e-8f);
#pragma unroll
    for (int rg = 0; rg < 4; rg++) {
      float inv = __shfl(inv_q, qd * 4 + rg);
      int s = q0w + qd * 4 + rg;
#pragma unroll
      for (int nsub = 0; nsub < 4; nsub++)
        op[(size_t)s * 1024 + nsub * 16 + la] = acco[nsub][rg] * inv;
    }
  }
}

extern "C" void kernel_launch(void* const* d_in, const int* in_sizes, int n_in,
                              void* d_out, int out_size, void* d_ws, size_t ws_size,
                              hipStream_t stream) {
  (void)in_sizes; (void)n_in; (void)out_size; (void)ws_size;
  const float* x = (const float*)d_in[0];
  const float* am = (const float*)d_in[1];
  const float* Wq = (const float*)d_in[2];
  const float* Wk = (const float*)d_in[3];
  const float* Wv = (const float*)d_in[4];
  float* out = (float*)d_out;

  char* p = (char*)d_ws;
  _Float16* xb = (_Float16*)p;    p += (size_t)8192 * 1024 * 2;
  _Float16* Wqkvt = (_Float16*)p; p += (size_t)3 * 1024 * 1024 * 2;
  _Float16* Qt = (_Float16*)p;    p += (size_t)8192 * 1024 * 2;   // [b,h,d,s]
  _Float16* Kh = (_Float16*)p;    p += (size_t)8192 * 1024 * 2;   // [b,h,s,d]
  _Float16* Vth = (_Float16*)p;   p += (size_t)8192 * 1024 * 2;   // [b,h,d,s]
  unsigned long long* mb = (unsigned long long*)p;

  prep_kernel<<<44032, 256, 0, stream>>>(x, am, Wq, Wk, Wv, xb, Wqkvt, mb);
  gemm_kernel<<<dim3(512), 512, 0, stream>>>(xb, Wqkvt, Qt, Kh, Vth);
  attn_kernel<<<1024, 512, 0, stream>>>(Qt, Kh, Vth, mb, out);
}

// Round 7
// 240.583 us; speedup vs baseline: 1.0846x; 1.0237x over previous
//
#include <hip/hip_runtime.h>

#define KDIM 1024

typedef _Float16 half8 __attribute__((ext_vector_type(8)));
typedef _Float16 half4 __attribute__((ext_vector_type(4)));
typedef __fp16 fp16x2 __attribute__((ext_vector_type(2)));
typedef __fp16 fp16x4 __attribute__((ext_vector_type(4)));
typedef float f32x4 __attribute__((ext_vector_type(4)));

#if defined(__has_builtin)
#if __has_builtin(__builtin_amdgcn_global_load_lds)
#define HAVE_GLDS 1
#endif
#if __has_builtin(__builtin_amdgcn_exp2f)
#define EXP2(x) __builtin_amdgcn_exp2f(x)
#endif
#if __has_builtin(__builtin_amdgcn_cvt_pkrtz)
#define HAVE_PKRTZ 1
#endif
#if __has_builtin(__builtin_amdgcn_fdot2)
#define HAVE_FDOT2 1
#endif
#endif
#ifndef EXP2
#define EXP2(x) exp2f(x)
#endif

__device__ __forceinline__ void stage16(const _Float16* g, _Float16* wave_base, int lane) {
#ifdef HAVE_GLDS
  __builtin_amdgcn_global_load_lds(
      (const __attribute__((address_space(1))) void*)g,
      (__attribute__((address_space(3))) void*)wave_base, 16, 0, 0);
#else
  *(half8*)(wave_base + lane * 8) = *(const half8*)g;
#endif
}

#define BARRIER() __builtin_amdgcn_s_barrier()

// ------------- merged prep: cast x | transpose-cast W | mask bits -------------
__global__ void prep_kernel(const float* __restrict__ x, const float* __restrict__ am,
                            const float* __restrict__ Wq, const float* __restrict__ Wk,
                            const float* __restrict__ Wv, _Float16* __restrict__ xb,
                            _Float16* __restrict__ Wqkvt, unsigned long long* __restrict__ bits) {
  __shared__ _Float16 tile[32][33];
  int bid = blockIdx.x;
  if (bid < 8192) {
    size_t i = ((size_t)bid * 256 + threadIdx.x) * 4;
    float4 v = *(const float4*)(x + i);
    half4 h = { (_Float16)v.x, (_Float16)v.y, (_Float16)v.z, (_Float16)v.w };
    *(half4*)(xb + i) = h;
  } else if (bid < 11264) {
    int zz = bid - 8192;
    int z = zz >> 10;
    int rem = zz & 1023;
    int bx = rem & 31, by = rem >> 5;
    const float* src = z == 0 ? Wq : (z == 1 ? Wk : Wv);
    _Float16* dst = Wqkvt + (size_t)z * KDIM * KDIM;
    float sc = (z == 0) ? 0.18033688011112042f : 1.0f;  // (1/8)*log2(e)
    int tx = threadIdx.x & 31, ty = threadIdx.x >> 5;
    int c0 = bx * 32, r0 = by * 32;
#pragma unroll
    for (int i = 0; i < 4; i++) {
      int r = r0 + ty + i * 8;
      tile[tx][ty + i * 8] = (_Float16)(src[(size_t)r * KDIM + c0 + tx] * sc);
    }
    __syncthreads();
#pragma unroll
    for (int i = 0; i < 4; i++) {
      int n = c0 + ty + i * 8;
      dst[(size_t)n * KDIM + r0 + tx] = tile[ty + i * 8][tx];
    }
  } else {
    size_t i = (size_t)(bid - 11264) * 256 + threadIdx.x;
    unsigned long long b = __ballot(am[i] != 0.0f);
    if ((threadIdx.x & 63) == 0) bits[i >> 6] = b;
  }
}

// ---------------- fused QKV GEMM, 256x192 tile, BK=32, 2 blocks/CU, 1 barrier/tile ----------
// LDS 56KB -> 2 resident blocks/CU; sibling block hides the syncthreads drain (m97 regime).
// Rows are 32 halves (64B) = 4 chunks of 16B.
// Swizzle: phys chunk c at row r holds logical chunk c ^ ((r>>1)&3); reader fetches logical
// chunk qd at phys qd ^ ((la>>1)&3). Staging applies the inverse on the GLOBAL source
// (LDS dest stays linear, as global_load_lds requires).
__global__ __launch_bounds__(512, 4)
void gemm_kernel(const _Float16* __restrict__ A, const _Float16* __restrict__ Bt,
                 _Float16* __restrict__ Qt, _Float16* __restrict__ Kh,
                 _Float16* __restrict__ Vth) {
  __shared__ _Float16 As[2 * 8192];   // [buf][256 rows][32]
  __shared__ _Float16 Bs[2 * 6144];   // [buf][192 rows][32]
  int tid = threadIdx.x;
  int lane = tid & 63, w = tid >> 6;
  int la = lane & 15, qd = lane >> 4;
  int wm = w & 1, wn = w >> 1;  // 2M x 4N waves; per-wave out 128 x 48 (3 n-frags strided 64)
  // XCD swizzle: 512 blocks, 64 consecutive wgs per XCD (512 % 8 == 0 -> bijective)
  int bid = blockIdx.x;
  int wg = (bid & 7) * 64 + (bid >> 3);
  int by = wg >> 4, bx = wg & 15;
  int m0 = by * 256, n0 = bx * 192;

  // staging: slice = 16 rows x 32 halves = 1KB/wave. lane ln: row ln>>2, phys chunk ln&3,
  // logical source chunk (ln&3) ^ ((ln>>3)&3)
  int srow = lane >> 2;
  int slc = ((lane & 3) ^ ((lane >> 3) & 3)) << 3;  // source chunk offset in halves
  const _Float16* Ab = A + (size_t)m0 * KDIM;
  const _Float16* Bb = Bt + (size_t)n0 * KDIM;
  const _Float16* pAa = Ab + (size_t)(w * 16 + srow) * KDIM + slc;
  const _Float16* pAb = Ab + (size_t)(128 + w * 16 + srow) * KDIM + slc;
  const _Float16* pBa = Bb + (size_t)(w * 16 + srow) * KDIM + slc;
  const _Float16* pBb = Bb + (size_t)(128 + w * 16 + srow) * KDIM + slc;  // waves 0-3 only

  _Float16* ldsA0 = As + w * 512;         // rows w*16..w*16+15
  _Float16* ldsA1 = As + 4096 + w * 512;  // rows 128+w*16..
  _Float16* ldsB0 = Bs + w * 512;
  _Float16* ldsB1 = Bs + 4096 + w * 512;  // rows 128..191 (waves 0-3)

  // read-side: logical chunk qd at phys chunk qd ^ ((la>>1)&3)
  const int rc = ((qd ^ ((la >> 1) & 3)) << 3);
  const _Float16* baseA = As + (wm * 64 + la) * 32 + rc;
  const _Float16* baseB = Bs + (wn * 16 + la) * 32 + rc;

  f32x4 acc[8][3] = {};
  half8 bf[3];

#define STAGE_AB(B)                                            \
  do {                                                         \
    stage16(pAa, ldsA0 + (B) * 8192, lane);                    \
    stage16(pAb, ldsA1 + (B) * 8192, lane);                    \
    stage16(pBa, ldsB0 + (B) * 6144, lane);                    \
    if (w < 4) stage16(pBb, ldsB1 + (B) * 6144, lane);         \
    pAa += 32; pAb += 32; pBa += 32; pBb += 32;                \
  } while (0)

// A-frag a = mh*4+mi lives at rows mh*128 + mi*16 (+wm*64+la): offset mh*4096 + mi*512 halves.
#define TILE(T, CUR, NXT)                                                       \
  do {                                                                          \
    if ((T) < 31) STAGE_AB(NXT);                                                \
    _Pragma("unroll") for (int nj = 0; nj < 3; ++nj)                            \
        bf[nj] = *(const half8*)(baseB + (CUR) * 6144 + nj * 2048);             \
    __builtin_amdgcn_s_setprio(1);                                              \
    _Pragma("unroll") for (int a = 0; a < 8; ++a) {                             \
      half8 afa = *(const half8*)(baseA + (CUR) * 8192 + (a >> 2) * 4096 +      \
                                  (a & 3) * 512);                               \
      _Pragma("unroll") for (int nj = 0; nj < 3; ++nj)                          \
          acc[a][nj] = __builtin_amdgcn_mfma_f32_16x16x32_f16(                  \
              afa, bf[nj], acc[a][nj], 0, 0, 0);                                \
    }                                                                           \
    __builtin_amdgcn_s_setprio(0);                                              \
    __syncthreads();                                                            \
  } while (0)

  // Prologue: stage tile 0 into buf 0, full drain barrier.
  STAGE_AB(0);
  __syncthreads();

#pragma unroll 1
  for (int tp = 0; tp < 16; ++tp) {
    TILE(2 * tp, 0, 1);
    TILE(2 * tp + 1, 1, 0);
  }

#undef TILE
#undef STAGE_AB

  // ---------------- epilogue (per-frag Q/K/V routing; acc[mh*4+mi][nj]) ----------
  int rr = lane >> 2, c4 = lane & 3;
  _Float16* ep = As + w * 1280;  // wave-private 16x72 transpose patch
#pragma unroll
  for (int mh = 0; mh < 2; ++mh) {
    int srow0 = m0 + mh * 128 + wm * 64;
    int b = srow0 >> 10, s0 = srow0 & 1023;
#pragma unroll
    for (int nj = 0; nj < 3; ++nj) {
      int colh = n0 + wn * 16 + nj * 64;
      int whichf = colh >> 10;       // 0:Q 1:K 2:V (uniform per wave,nj)
      int cm = colh & 1023;
      int hh = cm >> 6, d0 = cm & 63;
      if (whichf == 1) {
        _Float16* kb = Kh + (size_t)(b * 16 + hh) * 1024 * 64;
#pragma unroll
        for (int mi = 0; mi < 4; ++mi) {
          f32x4 v = acc[mh * 4 + mi][nj];
          int s = s0 + mi * 16 + qd * 4;
#pragma unroll
          for (int rg = 0; rg < 4; ++rg)
            kb[(size_t)(s + rg) * 64 + d0 + la] = (_Float16)v[rg];
        }
      } else {
        _Float16* dst = (whichf == 0) ? Qt : Vth;
#pragma unroll
        for (int mi = 0; mi < 4; ++mi) {
          f32x4 v = acc[mh * 4 + mi][nj];
          half4 hv = { (_Float16)v[0], (_Float16)v[1], (_Float16)v[2], (_Float16)v[3] };
          *(half4*)(ep + la * 72 + mi * 16 + qd * 4) = hv;  // row=d(la), col=s
        }
        half8 o0 = *(const half8*)(ep + rr * 72 + c4 * 16);
        half8 o1 = *(const half8*)(ep + rr * 72 + c4 * 16 + 8);
        _Float16* gp = dst + ((size_t)(b * 16 + hh) * 64 + d0 + rr) * 1024 + s0 + c4 * 16;
        *(half8*)gp = o0;
        *(half8*)(gp + 8) = o1;
      }
    }
  }
}

// ---------------- fused attention: R4 version (verified 67.0us) ----------
__global__ __launch_bounds__(512, 2)
void attn_kernel(const _Float16* __restrict__ Qt, const _Float16* __restrict__ K,
                 const _Float16* __restrict__ Vt, const unsigned long long* __restrict__ mbits,
                 float* __restrict__ out) {
  __shared__ _Float16 Ks[4][2 * 64 * 32];  // 4 buffers, 2-ahead pipeline (8KB each)
  __shared__ _Float16 Vs[2][2 * 64 * 40];  // [buf][tc=t/32][d][40 padded]
  int tid = threadIdx.x;
  int lane = tid & 63, w4 = tid >> 6;  // w4 0..7
  int la = lane & 15, qd = lane >> 4;
  int linear = blockIdx.x;
  int xlo = linear & 7;
  int tmp = linear >> 3;  // 0..63
  int qt = tmp & 3;
  int hb = (tmp >> 2) * 8 + xlo;  // 0..127
  int h = hb & 15, b = hb >> 4;
  const _Float16* Qp = Qt + (size_t)hb * 64 * 1024;  // [d][s]
  const _Float16* Kp = K + (size_t)hb * 1024 * 64;   // [s][d]
  const _Float16* Vp = Vt + (size_t)hb * 64 * 1024;  // [d][s]
  int q0w = qt * 256 + w4 * 16;  // qfrag qi adds qi*128
  half8 qf[2][2];
#pragma unroll
  for (int qi = 0; qi < 2; qi++)
#pragma unroll
    for (int ks = 0; ks < 2; ks++)
#pragma unroll
      for (int j = 0; j < 8; j++)
        qf[qi][ks][j] = Qp[(size_t)(ks * 32 + qd * 8 + j) * 1024 + q0w + qi * 128 + la];
  unsigned long long mq[2][4];
#pragma unroll
  for (int qi = 0; qi < 2; qi++) {
    const ulonglong2* mp =
        (const ulonglong2*)(mbits + ((size_t)b * 1024 + q0w + qi * 128 + la) * 16 + qd * 4);
    ulonglong2 m01 = mp[0];
    ulonglong2 m23 = mp[1];
    mq[qi][0] = m01.x; mq[qi][1] = m01.y; mq[qi][2] = m23.x; mq[qi][3] = m23.y;
  }
  f32x4 acco[2][4] = {};
  float rs[2] = {0.f, 0.f};
  int kt_t = (tid & 255) >> 2;
  int kt_d = (tid >> 8) * 32 + (((tid & 3) ^ ((tid >> 2) & 3) ^ ((tid >> 4) & 3)) << 3);
  int kc8 = ((qd ^ (la & 3) ^ (la >> 2)) << 3);
  int vd = tid >> 3;
  int vt = (tid & 7) * 8;
  int vs_off = (vt >= 32 ? 2560 : 0) + vd * 40 + (vt & 31);
#if defined(HAVE_FDOT2) && defined(HAVE_PKRTZ)
  fp16x2 one2 = { (__fp16)1.0f, (__fp16)1.0f };
#endif
  // prologue: issue V(0) first (oldest), then K(0), K(1); leave K(1) in flight.
  {
    half8 vv0 = *(const half8*)(Vp + (size_t)vd * 1024 + vt);
    __builtin_amdgcn_sched_barrier(0);
    stage16(Kp + (size_t)kt_t * 64 + kt_d, Ks[0] + w4 * 512, lane);
    stage16(Kp + (size_t)(64 + kt_t) * 64 + kt_d, Ks[1] + w4 * 512, lane);
    *(half8*)(Vs[0] + vs_off) = vv0;  // implicit wait retires vv0 (and nothing newer)
  }
  asm volatile("s_waitcnt vmcnt(1) lgkmcnt(0)" ::: "memory");
  BARRIER();
  for (int tt = 0; tt < 16; tt++) {
    const _Float16* ks_ = Ks[tt & 3];
    const _Float16* vs_ = Vs[tt & 1];
    half8 vvn;
    if (tt < 15) {
      vvn = *(const half8*)(Vp + (size_t)vd * 1024 + (tt + 1) * 64 + vt);
      __builtin_amdgcn_sched_barrier(0);
    }
    if (tt < 14)
      stage16(Kp + (size_t)((tt + 2) * 64 + kt_t) * 64 + kt_d, Ks[(tt + 2) & 3] + w4 * 512, lane);
    unsigned long long mw0 = __shfl(mq[0][tt & 3], ((tt >> 2) << 4) + la);
    unsigned long long mw1 = __shfl(mq[1][tt & 3], ((tt >> 2) << 4) + la);
    unsigned long long mq0s = mw0 >> (qd * 4);
    unsigned long long mq1s = mw1 >> (qd * 4);
#pragma unroll
    for (int tsub = 0; tsub < 4; tsub++) {
      half8 kf0 = *(const half8*)(ks_ + (tsub * 16 + la) * 32 + kc8);
      half8 kf1 = *(const half8*)(ks_ + 2048 + (tsub * 16 + la) * 32 + kc8);
      f32x4 a0 = {}, a1 = {};
      __builtin_amdgcn_s_setprio(1);
      a0 = __builtin_amdgcn_mfma_f32_16x16x32_f16(kf0, qf[0][0], a0, 0, 0, 0);
      a1 = __builtin_amdgcn_mfma_f32_16x16x32_f16(kf0, qf[1][0], a1, 0, 0, 0);
      a0 = __builtin_amdgcn_mfma_f32_16x16x32_f16(kf1, qf[0][1], a0, 0, 0, 0);
      a1 = __builtin_amdgcn_mfma_f32_16x16x32_f16(kf1, qf[1][1], a1, 0, 0, 0);
      __builtin_amdgcn_s_setprio(0);
      half4 pf[2];
#pragma unroll
      for (int qi = 0; qi < 2; qi++) {
        const f32x4& aa = qi ? a1 : a0;
        unsigned nib = (unsigned)((qi ? mq1s : mq0s) >> (tsub * 16)) & 15u;
        float e0 = (nib & 1u) ? EXP2(aa[0]) : 0.0f;
        float e1 = (nib & 2u) ? EXP2(aa[1]) : 0.0f;
        float e2 = (nib & 4u) ? EXP2(aa[2]) : 0.0f;
        float e3 = (nib & 8u) ? EXP2(aa[3]) : 0.0f;
#ifdef HAVE_PKRTZ
        fp16x2 p01 = __builtin_amdgcn_cvt_pkrtz(e0, e1);
        fp16x2 p23 = __builtin_amdgcn_cvt_pkrtz(e2, e3);
        fp16x4 pfv = __builtin_shufflevector(p01, p23, 0, 1, 2, 3);
        pf[qi] = __builtin_bit_cast(half4, pfv);
#else
        pf[qi][0] = (_Float16)e0; pf[qi][1] = (_Float16)e1;
        pf[qi][2] = (_Float16)e2; pf[qi][3] = (_Float16)e3;
#endif
#if defined(HAVE_FDOT2) && defined(HAVE_PKRTZ)
        rs[qi] = __builtin_amdgcn_fdot2(p01, one2, rs[qi], false);
        rs[qi] = __builtin_amdgcn_fdot2(p23, one2, rs[qi], false);
#else
        rs[qi] += e0 + e1 + e2 + e3;
#endif
      }
#pragma unroll
      for (int nsub = 0; nsub < 4; nsub++) {
        half4 vf = *(const half4*)(vs_ + (tsub >> 1) * 2560 + (nsub * 16 + la) * 40 +
                                   (tsub & 1) * 16 + qd * 4);
        __builtin_amdgcn_s_setprio(1);
        acco[0][nsub] = __builtin_amdgcn_mfma_f32_16x16x16f16(pf[0], vf, acco[0][nsub], 0, 0, 0);
        acco[1][nsub] = __builtin_amdgcn_mfma_f32_16x16x16f16(pf[1], vf, acco[1][nsub], 0, 0, 0);
        __builtin_amdgcn_s_setprio(0);
      }
    }
    if (tt < 15) *(half8*)(Vs[(tt + 1) & 1] + vs_off) = vvn;
    if (tt < 14) {
      asm volatile("s_waitcnt vmcnt(1) lgkmcnt(0)" ::: "memory");
      BARRIER();
    } else if (tt == 14) {
      asm volatile("s_waitcnt vmcnt(0) lgkmcnt(0)" ::: "memory");
      BARRIER();
    }
  }
  float* op = out + (size_t)b * 1024 * 1024 + (size_t)h * 64;
#pragma unroll
  for (int qi = 0; qi < 2; qi++) {
    float r0 = rs[qi];
    r0 += __shfl_xor(r0, 16);
    r0 += __shfl_xor(r0, 32);
    float inv_q = 1.0f / (r0 + 1e-8f);
#pragma unroll
    for (int rg = 0; rg < 4; rg++) {
      float inv = __shfl(inv_q, qd * 4 + rg);
      int s = q0w + qi * 128 + qd * 4 + rg;
#pragma unroll
      for (int nsub = 0; nsub < 4; nsub++)
        op[(size_t)s * 1024 + nsub * 16 + la] = acco[qi][nsub][rg] * inv;
    }
  }
}

extern "C" void kernel_launch(void* const* d_in, const int* in_sizes, int n_in,
                              void* d_out, int out_size, void* d_ws, size_t ws_size,
                              hipStream_t stream) {
  (void)in_sizes; (void)n_in; (void)out_size; (void)ws_size;
  const float* x = (const float*)d_in[0];
  const float* am = (const float*)d_in[1];
  const float* Wq = (const float*)d_in[2];
  const float* Wk = (const float*)d_in[3];
  const float* Wv = (const float*)d_in[4];
  float* out = (float*)d_out;

  char* p = (char*)d_ws;
  _Float16* xb = (_Float16*)p;    p += (size_t)8192 * 1024 * 2;
  _Float16* Wqkvt = (_Float16*)p; p += (size_t)3 * 1024 * 1024 * 2;
  _Float16* Qt = (_Float16*)p;    p += (size_t)8192 * 1024 * 2;   // [b,h,d,s]
  _Float16* Kh = (_Float16*)p;    p += (size_t)8192 * 1024 * 2;   // [b,h,s,d]
  _Float16* Vth = (_Float16*)p;   p += (size_t)8192 * 1024 * 2;   // [b,h,d,s]
  unsigned long long* mb = (unsigned long long*)p;

  prep_kernel<<<44032, 256, 0, stream>>>(x, am, Wq, Wk, Wv, xb, Wqkvt, mb);
  gemm_kernel<<<dim3(512), 512, 0, stream>>>(xb, Wqkvt, Qt, Kh, Vth);
  attn_kernel<<<512, 512, 0, stream>>>(Qt, Kh, Vth, mb, out);
}